// Round 7
// baseline (1163.189 us; speedup 1.0000x reference)
//
#include <hip/hip_runtime.h>
#include <stdint.h>

#define NB 8
#define NN 4096
#define NC 64
#define NS 1024
#define NK 32
#define NQ (NB*NS)        /* 8192 queries */
#define NP (NQ*NK)        /* 262144 positions */
#define EPSBN 1e-5f

typedef unsigned long long u64;
typedef float v2f __attribute__((ext_vector_type(2)));

__device__ __forceinline__ float lrelu(float x){ return x >= 0.0f ? x : 0.1f*x; }

// IEEE-total-order key: ascending key == ascending float
__device__ __forceinline__ unsigned int fkey(float d){
    unsigned int fb = __float_as_uint(d);
    return (fb & 0x80000000u) ? ~fb : (fb | 0x80000000u);
}

// sum-reduce (valid on lane 63 only)
__device__ __forceinline__ float wave_sum_f(float x){
    int v = __float_as_int(x);
    {int o=__builtin_amdgcn_update_dpp(0,v,0x111,0xf,0xf,true); v=__float_as_int(__int_as_float(v)+__int_as_float(o));}
    {int o=__builtin_amdgcn_update_dpp(0,v,0x112,0xf,0xf,true); v=__float_as_int(__int_as_float(v)+__int_as_float(o));}
    {int o=__builtin_amdgcn_update_dpp(0,v,0x114,0xf,0xf,true); v=__float_as_int(__int_as_float(v)+__int_as_float(o));}
    {int o=__builtin_amdgcn_update_dpp(0,v,0x118,0xf,0xf,true); v=__float_as_int(__int_as_float(v)+__int_as_float(o));}
    {int o=__builtin_amdgcn_update_dpp(0,v,0x142,0xf,0xf,true); v=__float_as_int(__int_as_float(v)+__int_as_float(o));}
    {int o=__builtin_amdgcn_update_dpp(0,v,0x143,0xf,0xf,true); v=__float_as_int(__int_as_float(v)+__int_as_float(o));}
    return __int_as_float(v);
}
// inclusive prefix-sum over 64 lanes (ints)
__device__ __forceinline__ int wave_incl_add(int x){
    int v = x;
    {int o=__builtin_amdgcn_update_dpp(0,v,0x111,0xf,0xf,true); v+=o;}
    {int o=__builtin_amdgcn_update_dpp(0,v,0x112,0xf,0xf,true); v+=o;}
    {int o=__builtin_amdgcn_update_dpp(0,v,0x114,0xf,0xf,true); v+=o;}
    {int o=__builtin_amdgcn_update_dpp(0,v,0x118,0xf,0xf,true); v+=o;}
    {int o=__builtin_amdgcn_update_dpp(0,v,0x142,0xa,0xf,true); v+=o;}
    {int o=__builtin_amdgcn_update_dpp(0,v,0x143,0xc,0xf,true); v+=o;}
    return v;
}
// f32 max-reduce, broadcast to all lanes via readlane 63
__device__ __forceinline__ float wave_max_f32(float x){
    int v = __float_as_int(x);
    {int o=__builtin_amdgcn_update_dpp(v,v,0x111,0xf,0xf,false); v=__float_as_int(fmaxf(__int_as_float(v),__int_as_float(o)));}
    {int o=__builtin_amdgcn_update_dpp(v,v,0x112,0xf,0xf,false); v=__float_as_int(fmaxf(__int_as_float(v),__int_as_float(o)));}
    {int o=__builtin_amdgcn_update_dpp(v,v,0x114,0xf,0xf,false); v=__float_as_int(fmaxf(__int_as_float(v),__int_as_float(o)));}
    {int o=__builtin_amdgcn_update_dpp(v,v,0x118,0xf,0xf,false); v=__float_as_int(fmaxf(__int_as_float(v),__int_as_float(o)));}
    {int o=__builtin_amdgcn_update_dpp(v,v,0x142,0xf,0xf,false); v=__float_as_int(fmaxf(__int_as_float(v),__int_as_float(o)));}
    {int o=__builtin_amdgcn_update_dpp(v,v,0x143,0xf,0xf,false); v=__float_as_int(fmaxf(__int_as_float(v),__int_as_float(o)));}
    return __int_as_float(__builtin_amdgcn_readlane(v, 63));
}

// ---------------------------------------------------------------------------
// FPS: one block/batch, 256 thr (4 waves), 16 pts/thread in regs.
// Per-point tracking: f32 max + cndmask idx (no per-point f64 pack).
// Wave: f32 DPP max + ballot/ffs (lane order == idx order -> first occ).
// Cross-wave: one packed f64 {dist_bits, ~idx} per wave, 4 LDS slots.
// Bit-exact vs numpy: rn ops, ((dx2+dy2)+dz2), min, first-occurrence argmax.
// ---------------------------------------------------------------------------
__global__ __launch_bounds__(256,1) void fps_kernel(const float* __restrict__ xyz,
                                                    float* __restrict__ out0,
                                                    float* __restrict__ nxyz)
{
    __shared__ float sX[NN], sY[NN], sZ[NN];
    __shared__ double slots[2][4];
    __shared__ int sFar[NS];
    const int b = blockIdx.x, t = threadIdx.x;
    const int lane = t & 63, wv = t >> 6;
    const float* base = xyz + (size_t)b*NN*3;
    for (int i = t; i < NN; i += 256){
        const float* pp = base + 3*i;
        sX[i] = pp[0]; sY[i] = pp[1]; sZ[i] = pp[2];
    }
    __syncthreads();
    v2f PX[8], PY[8], PZ[8], D[8];
    const int pb = t*16;
    #pragma unroll
    for (int j = 0; j < 8; ++j){
        PX[j] = (v2f){ sX[pb+2*j], sX[pb+2*j+1] };
        PY[j] = (v2f){ sY[pb+2*j], sY[pb+2*j+1] };
        PZ[j] = (v2f){ sZ[pb+2*j], sZ[pb+2*j+1] };
        D[j]  = (v2f){ 1e10f, 1e10f };
    }
    int far = 0;
    float cx = sX[0], cy = sY[0], cz = sZ[0];
    for (int s = 0; s < NS; ++s){
        if (t == 255) sFar[s] = far;
        float bd = -1.0f; int bidx = 0;
        {
            #pragma clang fp contract(off)
            v2f cx2 = (v2f){cx, cx}, cy2 = (v2f){cy, cy}, cz2 = (v2f){cz, cz};
            #pragma unroll
            for (int j = 0; j < 8; ++j){
                v2f dx = PX[j] - cx2;
                v2f dy = PY[j] - cy2;
                v2f dz = PZ[j] - cz2;
                v2f dd = (dx*dx + dy*dy) + dz*dz;
                v2f nd = __builtin_elementwise_min(D[j], dd);
                D[j] = nd;
                if (nd.x > bd){ bd = nd.x; bidx = pb + 2*j; }      // strict >
                if (nd.y > bd){ bd = nd.y; bidx = pb + 2*j + 1; }  // first-occ
            }
        }
        float wm = wave_max_f32(bd);
        u64 mask = __ballot(bd == wm);
        int L = __ffsll(mask) - 1;        // lowest lane = smallest idx
        const int par = s & 1;
        if (lane == L)
            slots[par][wv] = __hiloint2double(__float_as_int(wm), (int)(~(unsigned)bidx));
        __syncthreads();
        double s0 = slots[par][0], s1 = slots[par][1];
        double s2 = slots[par][2], s3 = slots[par][3];
        double mm = fmax(fmax(s0, s1), fmax(s2, s3));   // (dist, ~idx) lex max
        far = (int)(~(unsigned)__double2loint(mm));
        cx = sX[far]; cy = sY[far]; cz = sZ[far];
    }
    __syncthreads();
    for (int s = t; s < NS; s += 256){
        const int f = sFar[s];
        const float x = sX[f], y = sY[f], z = sZ[f];
        float* npq = nxyz + ((size_t)b*NS + s)*3;
        npq[0]=x; npq[1]=y; npq[2]=z;
        out0[(b*3+0)*NS+s]=x; out0[(b*3+1)*NS+s]=y; out0[(b*3+2)*NS+s]=z;
    }
}

// ---------------------------------------------------------------------------
// KNN: one wave per query; exact 32nd-smallest via 32-level bitwise binary
// search on fkey (pure VALU + DPP, no LDS/atomics). Ties -> smallest index.
// ---------------------------------------------------------------------------
__global__ __launch_bounds__(256,2) void knn_kernel(const float* __restrict__ xyz,
                                                    const float* __restrict__ nxyz,
                                                    int* __restrict__ kidx)
{
    const int t = threadIdx.x, lane = t & 63, w = t >> 6;
    const int q = blockIdx.x*4 + w;
    const int b = q >> 10;
    const float* base = xyz + (size_t)b*NN*3;
    const float* qp = nxyz + (size_t)q*3;
    const float qx = qp[0], qy = qp[1], qz = qp[2];
    const float qsq = __fadd_rn(__fadd_rn(__fmul_rn(qx,qx),__fmul_rn(qy,qy)),__fmul_rn(qz,qz));

    unsigned int key[64];
    #pragma unroll
    for (int i = 0; i < 64; ++i){
        const int idx = (i<<6) + lane;
        const float* pp = base + 3*idx;
        float x = pp[0], y = pp[1], z = pp[2];
        float dot = __fadd_rn(__fadd_rn(__fmul_rn(qx,x),__fmul_rn(qy,y)),__fmul_rn(qz,z));
        float psq = __fadd_rn(__fadd_rn(__fmul_rn(x,x),__fmul_rn(y,y)),__fmul_rn(z,z));
        float d = __fadd_rn(__fadd_rn(__fmul_rn(-2.0f,dot),qsq),psq);
        key[i] = fkey(d);
    }

    unsigned int pref = 0; int need = 32;
    for (int bit = 31; bit >= 0; --bit){
        const unsigned int bound = 1u << bit;
        int c = 0;
        #pragma unroll
        for (int i = 0; i < 64; ++i) c += ((key[i] ^ pref) < bound) ? 1 : 0;
        int tot = __builtin_amdgcn_readlane(wave_incl_add(c), 63);
        if (tot < need){ need -= tot; pref |= bound; }
    }
    const unsigned int T = pref;

    int cl = 0;
    #pragma unroll
    for (int i = 0; i < 64; ++i) cl += (key[i] < T) ? 1 : 0;
    int incl_cl = wave_incl_add(cl);
    int clx = incl_cl - cl;
    int tiebase = __builtin_amdgcn_readlane(incl_cl, 63);
    int* oq = kidx + (size_t)q*NK;
    int pos = clx;
    #pragma unroll
    for (int i = 0; i < 64; ++i){
        if (key[i] < T){ oq[pos] = (i<<6) + lane; ++pos; }
    }
    int tcount = 0;
    for (int i = 0; i < 64 && tcount < need; ++i){
        u64 m = __ballot(key[i] == T);
        int myrank = (int)__popcll(m & ((1ull << lane) - 1ull));
        if ((key[i] == T) && (tcount + myrank < need))
            oq[tiebase + tcount + myrank] = (i<<6) + lane;
        tcount += (int)__popcll(m);
    }
}

// ---------------------------------------------------------------------------
// Weight transpose: Wt[m][c][o] = W_m[o][c]  (5 matrices, one launch)
// ---------------------------------------------------------------------------
__global__ __launch_bounds__(256) void wtrans_kernel(const float* __restrict__ w0,
    const float* __restrict__ w1, const float* __restrict__ w2,
    const float* __restrict__ w3, const float* __restrict__ w4,
    float* __restrict__ dst)
{
    const float* s;
    switch (blockIdx.x){
        case 0: s = w0; break; case 1: s = w1; break; case 2: s = w2; break;
        case 3: s = w3; break; default: s = w4; break;
    }
    float* d = dst + (size_t)blockIdx.x*4096;
    for (int i = threadIdx.x; i < 4096; i += 256){
        int o = i >> 6, c = i & 63;
        d[c*64 + o] = s[i];
    }
}

// ---------------------------------------------------------------------------
// Gather: x0[c][p] = features[b, kidx[p], c]   (layout [C, NP])
// ---------------------------------------------------------------------------
__global__ __launch_bounds__(256,2) void gather_kernel(const float* __restrict__ features,
                                                       const int* __restrict__ kidx,
                                                       float* __restrict__ x0)
{
    const int p = blockIdx.x*256 + threadIdx.x;
    const int b = p >> 15;
    const int idx = kidx[p];
    const float4* f = (const float4*)(features + ((size_t)b*NN + idx)*NC);
    #pragma unroll
    for (int c4 = 0; c4 < 16; ++c4){
        float4 v = f[c4];
        x0[(size_t)(4*c4+0)*NP + p] = v.x;
        x0[(size_t)(4*c4+1)*NP + p] = v.y;
        x0[(size_t)(4*c4+2)*NP + p] = v.z;
        x0[(size_t)(4*c4+3)*NP + p] = v.w;
    }
}

// ---------------------------------------------------------------------------
// Conv 1x1 + fused BN stats. 2 pos/thread (float2), 32 outs, 64 VGPR acc ->
// 512 blocks, ~2 blocks/CU co-resident. If pin != null: compute input affine
// in-kernel from producer partials, apply affine+leaky on input.
// partials layout: [half(2)][bp(256)][stat(64)]  (stat 0..31 sum, 32..63 sq)
// ---------------------------------------------------------------------------
__global__ __launch_bounds__(512,2) void conv_kernel(const float* __restrict__ in,
    float* __restrict__ out, const float* __restrict__ Wt, const float* __restrict__ bias,
    const float* __restrict__ pin, const float* __restrict__ g,
    const float* __restrict__ beta, float* __restrict__ affout,
    float* __restrict__ pout)
{
    __shared__ float sAff[128];
    __shared__ float sRed[8][64];
    const int t = threadIdx.x, lane = t & 63, wv = t >> 6;
    const int bo = blockIdx.x & 1, bp = blockIdx.x >> 1;   // bp in [0,256)
    const int obase = bo*32;
    const int p0 = bp*1024 + wv*128 + lane*2;              // 2 consecutive pos
    const int apply_act = (pin != nullptr);

    if (apply_act){
        if (t < 64){
            const int half = t >> 5, oo = t & 31;
            const float* pb1 = pin + (size_t)half*16384;
            float S1 = 0.0f, S2 = 0.0f;
            #pragma unroll 8
            for (int i = 0; i < 256; ++i){
                S1 += pb1[i*64 + oo];
                S2 += pb1[i*64 + 32 + oo];
            }
            float mean = S1 * (1.0f/(float)NP);
            float var  = fmaxf(S2 * (1.0f/(float)NP) - mean*mean, 0.0f);
            float sc = g[t] * rsqrtf(var + EPSBN);
            sAff[t]    = sc;
            sAff[64+t] = beta[t] - mean*sc;
            if (affout){ affout[t] = sc; affout[64+t] = sAff[64+t]; }
        }
        __syncthreads();
    }

    float acc[2][32];
    #pragma unroll
    for (int o = 0; o < 32; ++o){
        float bb = bias[obase + o];
        acc[0][o]=bb; acc[1][o]=bb;
    }
    #pragma unroll 4
    for (int c = 0; c < 64; ++c){
        float2 x2 = *(const float2*)(in + (size_t)c*NP + p0);
        float xv[2] = {x2.x, x2.y};
        if (apply_act){
            float sc = sAff[c], sh = sAff[64+c];
            #pragma unroll
            for (int j = 0; j < 2; ++j){
                float v = fmaf(sc, xv[j], sh);
                xv[j] = v >= 0.0f ? v : 0.1f*v;
            }
        }
        const float4* wr = (const float4*)(Wt + c*64 + obase);   // uniform -> s_load
        #pragma unroll
        for (int o4 = 0; o4 < 8; ++o4){
            float4 w = wr[o4];
            #pragma unroll
            for (int j = 0; j < 2; ++j){
                acc[j][4*o4+0] = fmaf(w.x, xv[j], acc[j][4*o4+0]);
                acc[j][4*o4+1] = fmaf(w.y, xv[j], acc[j][4*o4+1]);
                acc[j][4*o4+2] = fmaf(w.z, xv[j], acc[j][4*o4+2]);
                acc[j][4*o4+3] = fmaf(w.w, xv[j], acc[j][4*o4+3]);
            }
        }
    }
    #pragma unroll
    for (int o = 0; o < 32; ++o){
        float2 r = make_float2(acc[0][o], acc[1][o]);
        *(float2*)(out + (size_t)(obase+o)*NP + p0) = r;
    }
    // fused BN stats
    #pragma unroll
    for (int o = 0; o < 32; ++o){
        float a0=acc[0][o], a1=acc[1][o];
        float s1 = a0+a1;
        float s2 = a0*a0+a1*a1;
        float t1 = wave_sum_f(s1);
        float t2 = wave_sum_f(s2);
        if (lane == 63){ sRed[wv][o] = t1; sRed[wv][32+o] = t2; }
    }
    __syncthreads();
    if (t < 64){
        float v = 0.0f;
        #pragma unroll
        for (int w8 = 0; w8 < 8; ++w8) v += sRed[w8][t];
        pout[(size_t)bo*16384 + bp*64 + t] = v;
    }
}

// ---------------------------------------------------------------------------
// Residual: x2 = leaky(affV(v) + leaky(affY(yt))). affV computed in-kernel
// from partials of v's conv (256 rows, 1 row/thread); affY from affx.
// ---------------------------------------------------------------------------
__global__ __launch_bounds__(256,2) void resid_kernel(const float* __restrict__ v,
    const float* __restrict__ yt, float* __restrict__ x2,
    const float* __restrict__ pin, const float* __restrict__ g,
    const float* __restrict__ beta, const float* __restrict__ affY)
{
    __shared__ float sPr[8];
    const int t = threadIdx.x, lane = t & 63, wv = t >> 6;
    const int c = blockIdx.x >> 4;                 // 16 blocks per channel
    {
        const int half = c >> 5, oo = c & 31;
        float a1 = pin[(size_t)half*16384 + t*64 + oo];
        float a2 = pin[(size_t)half*16384 + t*64 + 32 + oo];
        float r1 = wave_sum_f(a1);
        float r2 = wave_sum_f(a2);
        if (lane == 63){ sPr[wv*2] = r1; sPr[wv*2+1] = r2; }
    }
    __syncthreads();
    float S1 = sPr[0]+sPr[2]+sPr[4]+sPr[6];
    float S2 = sPr[1]+sPr[3]+sPr[5]+sPr[7];
    float mean = S1 * (1.0f/(float)NP);
    float var  = fmaxf(S2 * (1.0f/(float)NP) - mean*mean, 0.0f);
    const float va = g[c] * rsqrtf(var + EPSBN);
    const float vb = beta[c] - mean*va;
    const float ya = affY[c], yb = affY[64+c];
    const size_t e0 = (size_t)blockIdx.x*4096 + t;
    #pragma unroll
    for (int i = 0; i < 16; ++i){
        const size_t e = e0 + i*256;
        const float4 vv = ((const float4*)v)[e];
        const float4 yy = ((const float4*)yt)[e];
        float4 r;
        r.x = lrelu(fmaf(va, vv.x, vb) + lrelu(fmaf(ya, yy.x, yb)));
        r.y = lrelu(fmaf(va, vv.y, vb) + lrelu(fmaf(ya, yy.y, yb)));
        r.z = lrelu(fmaf(va, vv.z, vb) + lrelu(fmaf(ya, yy.z, yb)));
        r.w = lrelu(fmaf(va, vv.w, vb) + lrelu(fmaf(ya, yy.w, yb)));
        ((float4*)x2)[e] = r;
    }
}

// ---------------------------------------------------------------------------
// Final: x3 = leaky(aff(v2) + x2); out1[b,c,s] = max_k x3. Aff in-kernel.
// ---------------------------------------------------------------------------
__global__ __launch_bounds__(256,2) void final_kernel(const float* __restrict__ v2,
    const float* __restrict__ x2, const float* __restrict__ pin,
    const float* __restrict__ g, const float* __restrict__ beta,
    float* __restrict__ out1)
{
    __shared__ float sPr[8];
    const int t = threadIdx.x, lane = t & 63, wv = t >> 6;
    const int c = blockIdx.x >> 5;                 // 32 blocks per channel
    {
        const int half = c >> 5, oo = c & 31;
        float a1 = pin[(size_t)half*16384 + t*64 + oo];
        float a2 = pin[(size_t)half*16384 + t*64 + 32 + oo];
        float r1 = wave_sum_f(a1);
        float r2 = wave_sum_f(a2);
        if (lane == 63){ sPr[wv*2] = r1; sPr[wv*2+1] = r2; }
    }
    __syncthreads();
    float S1 = sPr[0]+sPr[2]+sPr[4]+sPr[6];
    float S2 = sPr[1]+sPr[3]+sPr[5]+sPr[7];
    float mean = S1 * (1.0f/(float)NP);
    float var  = fmaxf(S2 * (1.0f/(float)NP) - mean*mean, 0.0f);
    const float a = g[c] * rsqrtf(var + EPSBN);
    const float sh = beta[c] - mean*a;

    const int gg = blockIdx.x*256 + t;
    const int bs = gg & 8191;
    const float4* pv = (const float4*)(v2 + (size_t)c*NP + (size_t)bs*NK);
    const float4* px = (const float4*)(x2 + (size_t)c*NP + (size_t)bs*NK);
    float m = -3.0e38f;
    #pragma unroll
    for (int i = 0; i < 8; ++i){
        float4 av = pv[i], xv = px[i];
        m = fmaxf(m, lrelu(fmaf(a, av.x, sh) + xv.x));
        m = fmaxf(m, lrelu(fmaf(a, av.y, sh) + xv.y));
        m = fmaxf(m, lrelu(fmaf(a, av.z, sh) + xv.z));
        m = fmaxf(m, lrelu(fmaf(a, av.w, sh) + xv.w));
    }
    const int b = bs >> 10, s = bs & 1023;
    out1[((size_t)b*NC + c)*NS + s] = m;
}

// ---------------------------------------------------------------------------
extern "C" void kernel_launch(void* const* d_in, const int* in_sizes, int n_in,
                              void* d_out, int out_size, void* d_ws, size_t ws_size,
                              hipStream_t stream)
{
    const float* xyz      = (const float*)d_in[0];
    const float* features = (const float*)d_in[1];
    const float* w_t    = (const float*)d_in[2];
    const float* w1_0   = (const float*)d_in[3];
    const float* w2_0   = (const float*)d_in[4];
    const float* w1_1   = (const float*)d_in[5];
    const float* w2_1   = (const float*)d_in[6];
    const float* b_t    = (const float*)d_in[7];
    const float* b1_0   = (const float*)d_in[8];
    const float* b2_0   = (const float*)d_in[9];
    const float* b1_1   = (const float*)d_in[10];
    const float* b2_1   = (const float*)d_in[11];
    const float* g_t    = (const float*)d_in[12];
    const float* g1_0   = (const float*)d_in[13];
    const float* g2_0   = (const float*)d_in[14];
    const float* g1_1   = (const float*)d_in[15];
    const float* g2_1   = (const float*)d_in[16];
    const float* beta_t  = (const float*)d_in[17];
    const float* beta1_0 = (const float*)d_in[18];
    const float* beta2_0 = (const float*)d_in[19];
    const float* beta1_1 = (const float*)d_in[20];
    const float* beta2_1 = (const float*)d_in[21];

    float* out = (float*)d_out;

    float* buf0  = (float*)d_ws;
    float* buf1  = buf0 + (size_t)NC*NP;
    float* buf2  = buf1 + (size_t)NC*NP;
    float* nxyz  = buf2 + (size_t)NC*NP;                 // NB*NS*3
    int*   kidx  = (int*)(nxyz + (size_t)NB*NS*3);       // NP ints
    float* pT    = (float*)(kidx + NP);                  // 5 x 32768 partials
    float* p10   = pT  + 32768;
    float* p20   = p10 + 32768;
    float* p11   = p20 + 32768;
    float* p21   = p11 + 32768;
    float* affx  = p21 + 32768;                          // 128 (aff_t for resid)
    float* wt    = affx + 128;                           // 5*4096

    wtrans_kernel<<<5, 256, 0, stream>>>(w_t, w1_0, w2_0, w1_1, w2_1, wt);
    fps_kernel<<<NB, 256, 0, stream>>>(xyz, out, nxyz);
    knn_kernel<<<NQ/4, 256, 0, stream>>>(xyz, nxyz, kidx);
    gather_kernel<<<NP/256, 256, 0, stream>>>(features, kidx, buf0);

    // stage t  (no input affine)
    conv_kernel<<<512, 512, 0, stream>>>(buf0, buf1, wt + 0*4096, b_t,
                                         nullptr, nullptr, nullptr, nullptr, pT);
    // resblock 0
    conv_kernel<<<512, 512, 0, stream>>>(buf1, buf0, wt + 1*4096, b1_0,
                                         pT, g_t, beta_t, affx, p10);
    conv_kernel<<<512, 512, 0, stream>>>(buf0, buf2, wt + 2*4096, b2_0,
                                         p10, g1_0, beta1_0, nullptr, p20);
    resid_kernel<<<1024, 256, 0, stream>>>(buf2, buf1, buf0,
                                           p20, g2_0, beta2_0, affx);
    // resblock 1  (input already activated)
    conv_kernel<<<512, 512, 0, stream>>>(buf0, buf1, wt + 3*4096, b1_1,
                                         nullptr, nullptr, nullptr, nullptr, p11);
    conv_kernel<<<512, 512, 0, stream>>>(buf1, buf2, wt + 4*4096, b2_1,
                                         p11, g1_1, beta1_1, nullptr, p21);
    // epilogue: residual + max over K
    final_kernel<<<2048, 256, 0, stream>>>(buf2, buf0, p21, g2_1, beta2_1,
                                           out + (size_t)NB*3*NS);
}

// Round 8
// 1094.086 us; speedup vs baseline: 1.0632x; 1.0632x over previous
//
#include <hip/hip_runtime.h>
#include <stdint.h>

#define NB 8
#define NN 4096
#define NC 64
#define NS 1024
#define NK 32
#define NQ (NB*NS)        /* 8192 queries */
#define NP (NQ*NK)        /* 262144 positions */
#define EPSBN 1e-5f

typedef unsigned long long u64;
typedef float v2f __attribute__((ext_vector_type(2)));

__device__ __forceinline__ float lrelu(float x){ return x >= 0.0f ? x : 0.1f*x; }

// IEEE-total-order key: ascending key == ascending float
__device__ __forceinline__ unsigned int fkey(float d){
    unsigned int fb = __float_as_uint(d);
    return (fb & 0x80000000u) ? ~fb : (fb | 0x80000000u);
}

// sum-reduce (valid on lane 63 only)
__device__ __forceinline__ float wave_sum_f(float x){
    int v = __float_as_int(x);
    {int o=__builtin_amdgcn_update_dpp(0,v,0x111,0xf,0xf,true); v=__float_as_int(__int_as_float(v)+__int_as_float(o));}
    {int o=__builtin_amdgcn_update_dpp(0,v,0x112,0xf,0xf,true); v=__float_as_int(__int_as_float(v)+__int_as_float(o));}
    {int o=__builtin_amdgcn_update_dpp(0,v,0x114,0xf,0xf,true); v=__float_as_int(__int_as_float(v)+__int_as_float(o));}
    {int o=__builtin_amdgcn_update_dpp(0,v,0x118,0xf,0xf,true); v=__float_as_int(__int_as_float(v)+__int_as_float(o));}
    {int o=__builtin_amdgcn_update_dpp(0,v,0x142,0xf,0xf,true); v=__float_as_int(__int_as_float(v)+__int_as_float(o));}
    {int o=__builtin_amdgcn_update_dpp(0,v,0x143,0xf,0xf,true); v=__float_as_int(__int_as_float(v)+__int_as_float(o));}
    return __int_as_float(v);
}
// inclusive prefix-sum over 64 lanes (ints)
__device__ __forceinline__ int wave_incl_add(int x){
    int v = x;
    {int o=__builtin_amdgcn_update_dpp(0,v,0x111,0xf,0xf,true); v+=o;}
    {int o=__builtin_amdgcn_update_dpp(0,v,0x112,0xf,0xf,true); v+=o;}
    {int o=__builtin_amdgcn_update_dpp(0,v,0x114,0xf,0xf,true); v+=o;}
    {int o=__builtin_amdgcn_update_dpp(0,v,0x118,0xf,0xf,true); v+=o;}
    {int o=__builtin_amdgcn_update_dpp(0,v,0x142,0xa,0xf,true); v+=o;}
    {int o=__builtin_amdgcn_update_dpp(0,v,0x143,0xc,0xf,true); v+=o;}
    return v;
}
// max-reduce of a packed positive double across the wave, via DPP pairs
__device__ __forceinline__ double wave_max_d(double x){
    int lo = __double2loint(x), hi = __double2hiint(x);
    #define FPS_STG(ctl) { \
        int nl=__builtin_amdgcn_update_dpp(lo,lo,ctl,0xf,0xf,false); \
        int nh=__builtin_amdgcn_update_dpp(hi,hi,ctl,0xf,0xf,false); \
        double mx=fmax(__hiloint2double(hi,lo), __hiloint2double(nh,nl)); \
        lo=__double2loint(mx); hi=__double2hiint(mx); }
    FPS_STG(0x111) FPS_STG(0x112) FPS_STG(0x114) FPS_STG(0x118) FPS_STG(0x142) FPS_STG(0x143)
    #undef FPS_STG
    int flo = __builtin_amdgcn_readlane(lo, 63);
    int fhi = __builtin_amdgcn_readlane(hi, 63);
    return __hiloint2double(fhi, flo);
}

// ---------------------------------------------------------------------------
// FPS (r6 best-measured variant, 528 us): one block/batch, 256 thr, 16 pts/
// thread in regs, v2f update (pk f32, contract off), per-point packed f64
// argmax key {hi=dist_bits, lo=~idx} via v_max_f64; DPP wave reduce; 4 LDS
// slots. Bit-exact vs numpy: rn ops, ((dx2+dy2)+dz2), min, first-occurrence.
// ---------------------------------------------------------------------------
__global__ __launch_bounds__(256,1) void fps_kernel(const float* __restrict__ xyz,
                                                    float* __restrict__ out0,
                                                    float* __restrict__ nxyz)
{
    __shared__ float sX[NN], sY[NN], sZ[NN];
    __shared__ double slots[2][4];
    __shared__ int sFar[NS];
    const int b = blockIdx.x, t = threadIdx.x;
    const int lane = t & 63, wv = t >> 6;
    const float* base = xyz + (size_t)b*NN*3;
    for (int i = t; i < NN; i += 256){
        const float* pp = base + 3*i;
        sX[i] = pp[0]; sY[i] = pp[1]; sZ[i] = pp[2];
    }
    __syncthreads();
    v2f PX[8], PY[8], PZ[8], D[8];
    int LO[16];
    const int pb = t*16;
    #pragma unroll
    for (int j = 0; j < 8; ++j){
        PX[j] = (v2f){ sX[pb+2*j], sX[pb+2*j+1] };
        PY[j] = (v2f){ sY[pb+2*j], sY[pb+2*j+1] };
        PZ[j] = (v2f){ sZ[pb+2*j], sZ[pb+2*j+1] };
        D[j]  = (v2f){ 1e10f, 1e10f };
    }
    #pragma unroll
    for (int j = 0; j < 16; ++j) LO[j] = (int)(~(unsigned)(pb + j));
    int far = 0;
    float cx = sX[0], cy = sY[0], cz = sZ[0];
    for (int s = 0; s < NS; ++s){
        if (t == 255) sFar[s] = far;
        double best;
        {
            #pragma clang fp contract(off)
            v2f cx2 = (v2f){cx, cx}, cy2 = (v2f){cy, cy}, cz2 = (v2f){cz, cz};
            best = -1.0;
            #pragma unroll
            for (int j = 0; j < 8; ++j){
                v2f dx = PX[j] - cx2;
                v2f dy = PY[j] - cy2;
                v2f dz = PZ[j] - cz2;
                v2f dd = (dx*dx + dy*dy) + dz*dz;
                v2f nd = __builtin_elementwise_min(D[j], dd);
                D[j] = nd;
                best = fmax(best, __hiloint2double(__float_as_int(nd.x), LO[2*j]));
                best = fmax(best, __hiloint2double(__float_as_int(nd.y), LO[2*j+1]));
            }
        }
        double wb = wave_max_d(best);
        const int par = s & 1;
        if (lane == 0) slots[par][wv] = wb;
        __syncthreads();
        double s0 = slots[par][0], s1 = slots[par][1];
        double s2 = slots[par][2], s3 = slots[par][3];
        double mm = fmax(fmax(s0, s1), fmax(s2, s3));
        far = (int)(~(unsigned)__double2loint(mm));
        cx = sX[far]; cy = sY[far]; cz = sZ[far];
    }
    __syncthreads();
    for (int s = t; s < NS; s += 256){
        const int f = sFar[s];
        const float x = sX[f], y = sY[f], z = sZ[f];
        float* npq = nxyz + ((size_t)b*NS + s)*3;
        npq[0]=x; npq[1]=y; npq[2]=z;
        out0[(b*3+0)*NS+s]=x; out0[(b*3+1)*NS+s]=y; out0[(b*3+2)*NS+s]=z;
    }
}

// ---------------------------------------------------------------------------
// KNN: one wave per query; exact 32nd-smallest via 32-level bitwise binary
// search on fkey (pure VALU + DPP, no LDS/atomics). Ties -> smallest index.
// ---------------------------------------------------------------------------
__global__ __launch_bounds__(256,2) void knn_kernel(const float* __restrict__ xyz,
                                                    const float* __restrict__ nxyz,
                                                    int* __restrict__ kidx)
{
    const int t = threadIdx.x, lane = t & 63, w = t >> 6;
    const int q = blockIdx.x*4 + w;
    const int b = q >> 10;
    const float* base = xyz + (size_t)b*NN*3;
    const float* qp = nxyz + (size_t)q*3;
    const float qx = qp[0], qy = qp[1], qz = qp[2];
    const float qsq = __fadd_rn(__fadd_rn(__fmul_rn(qx,qx),__fmul_rn(qy,qy)),__fmul_rn(qz,qz));

    unsigned int key[64];
    #pragma unroll
    for (int i = 0; i < 64; ++i){
        const int idx = (i<<6) + lane;
        const float* pp = base + 3*idx;
        float x = pp[0], y = pp[1], z = pp[2];
        float dot = __fadd_rn(__fadd_rn(__fmul_rn(qx,x),__fmul_rn(qy,y)),__fmul_rn(qz,z));
        float psq = __fadd_rn(__fadd_rn(__fmul_rn(x,x),__fmul_rn(y,y)),__fmul_rn(z,z));
        float d = __fadd_rn(__fadd_rn(__fmul_rn(-2.0f,dot),qsq),psq);
        key[i] = fkey(d);
    }

    unsigned int pref = 0; int need = 32;
    for (int bit = 31; bit >= 0; --bit){
        const unsigned int bound = 1u << bit;
        int c = 0;
        #pragma unroll
        for (int i = 0; i < 64; ++i) c += ((key[i] ^ pref) < bound) ? 1 : 0;
        int tot = __builtin_amdgcn_readlane(wave_incl_add(c), 63);
        if (tot < need){ need -= tot; pref |= bound; }
    }
    const unsigned int T = pref;

    int cl = 0;
    #pragma unroll
    for (int i = 0; i < 64; ++i) cl += (key[i] < T) ? 1 : 0;
    int incl_cl = wave_incl_add(cl);
    int clx = incl_cl - cl;
    int tiebase = __builtin_amdgcn_readlane(incl_cl, 63);
    int* oq = kidx + (size_t)q*NK;
    int pos = clx;
    #pragma unroll
    for (int i = 0; i < 64; ++i){
        if (key[i] < T){ oq[pos] = (i<<6) + lane; ++pos; }
    }
    int tcount = 0;
    for (int i = 0; i < 64 && tcount < need; ++i){
        u64 m = __ballot(key[i] == T);
        int myrank = (int)__popcll(m & ((1ull << lane) - 1ull));
        if ((key[i] == T) && (tcount + myrank < need))
            oq[tiebase + tcount + myrank] = (i<<6) + lane;
        tcount += (int)__popcll(m);
    }
}

// ---------------------------------------------------------------------------
// Weight transpose: Wt[m][c][o] = W_m[o][c]  (5 matrices, one launch)
// ---------------------------------------------------------------------------
__global__ __launch_bounds__(256) void wtrans_kernel(const float* __restrict__ w0,
    const float* __restrict__ w1, const float* __restrict__ w2,
    const float* __restrict__ w3, const float* __restrict__ w4,
    float* __restrict__ dst)
{
    const float* s;
    switch (blockIdx.x){
        case 0: s = w0; break; case 1: s = w1; break; case 2: s = w2; break;
        case 3: s = w3; break; default: s = w4; break;
    }
    float* d = dst + (size_t)blockIdx.x*4096;
    for (int i = threadIdx.x; i < 4096; i += 256){
        int o = i >> 6, c = i & 63;
        d[c*64 + o] = s[i];
    }
}

// ---------------------------------------------------------------------------
// Fused gather + conv_t: input loads are the gathered feature rows directly
// (features is 8 MB -> L2/L3-resident; bo-duplicate reads are cache hits).
// Eliminates the 64MB gather write + 64MB conv_t re-read.
// Output/stats structure identical to conv_kernel (no input affine).
// ---------------------------------------------------------------------------
__global__ __launch_bounds__(512,2) void gconv_kernel(const float* __restrict__ features,
    const int* __restrict__ kidx, float* __restrict__ out,
    const float* __restrict__ Wt, const float* __restrict__ bias,
    float* __restrict__ pout)
{
    __shared__ float sRed[8][64];
    const int t = threadIdx.x, lane = t & 63, wv = t >> 6;
    const int bo = blockIdx.x & 1, bp = blockIdx.x >> 1;
    const int obase = bo*32;
    const int p0 = bp*1024 + wv*128 + lane*2;
    const int b = p0 >> 15;
    const int i0 = kidx[p0], i1 = kidx[p0+1];
    const float4* f0 = (const float4*)(features + ((size_t)b*NN + i0)*NC);
    const float4* f1 = (const float4*)(features + ((size_t)b*NN + i1)*NC);

    float acc[2][32];
    #pragma unroll
    for (int o = 0; o < 32; ++o){
        float bb = bias[obase + o];
        acc[0][o]=bb; acc[1][o]=bb;
    }
    #pragma unroll 4
    for (int c4 = 0; c4 < 16; ++c4){
        float4 xa = f0[c4], xb = f1[c4];
        float va[4] = {xa.x, xa.y, xa.z, xa.w};
        float vb[4] = {xb.x, xb.y, xb.z, xb.w};
        #pragma unroll
        for (int cc = 0; cc < 4; ++cc){
            const int c = 4*c4 + cc;
            const float4* wr = (const float4*)(Wt + c*64 + obase);
            #pragma unroll
            for (int o4 = 0; o4 < 8; ++o4){
                float4 w = wr[o4];
                acc[0][4*o4+0] = fmaf(w.x, va[cc], acc[0][4*o4+0]);
                acc[0][4*o4+1] = fmaf(w.y, va[cc], acc[0][4*o4+1]);
                acc[0][4*o4+2] = fmaf(w.z, va[cc], acc[0][4*o4+2]);
                acc[0][4*o4+3] = fmaf(w.w, va[cc], acc[0][4*o4+3]);
                acc[1][4*o4+0] = fmaf(w.x, vb[cc], acc[1][4*o4+0]);
                acc[1][4*o4+1] = fmaf(w.y, vb[cc], acc[1][4*o4+1]);
                acc[1][4*o4+2] = fmaf(w.z, vb[cc], acc[1][4*o4+2]);
                acc[1][4*o4+3] = fmaf(w.w, vb[cc], acc[1][4*o4+3]);
            }
        }
    }
    #pragma unroll
    for (int o = 0; o < 32; ++o){
        float2 r = make_float2(acc[0][o], acc[1][o]);
        *(float2*)(out + (size_t)(obase+o)*NP + p0) = r;
    }
    #pragma unroll
    for (int o = 0; o < 32; ++o){
        float a0=acc[0][o], a1=acc[1][o];
        float t1 = wave_sum_f(a0+a1);
        float t2 = wave_sum_f(a0*a0+a1*a1);
        if (lane == 63){ sRed[wv][o] = t1; sRed[wv][32+o] = t2; }
    }
    __syncthreads();
    if (t < 64){
        float v = 0.0f;
        #pragma unroll
        for (int w8 = 0; w8 < 8; ++w8) v += sRed[w8][t];
        pout[(size_t)bo*16384 + bp*64 + t] = v;
    }
}

// ---------------------------------------------------------------------------
// Conv 1x1 + fused BN stats. 2 pos/thread (float2), 32 outs, 512 blocks.
// If pin != null: compute input affine in-kernel from producer partials.
// partials layout: [half(2)][bp(256)][stat(64)]
// ---------------------------------------------------------------------------
__global__ __launch_bounds__(512,2) void conv_kernel(const float* __restrict__ in,
    float* __restrict__ out, const float* __restrict__ Wt, const float* __restrict__ bias,
    const float* __restrict__ pin, const float* __restrict__ g,
    const float* __restrict__ beta, float* __restrict__ affout,
    float* __restrict__ pout)
{
    __shared__ float sAff[128];
    __shared__ float sRed[8][64];
    const int t = threadIdx.x, lane = t & 63, wv = t >> 6;
    const int bo = blockIdx.x & 1, bp = blockIdx.x >> 1;   // bp in [0,256)
    const int obase = bo*32;
    const int p0 = bp*1024 + wv*128 + lane*2;              // 2 consecutive pos
    const int apply_act = (pin != nullptr);

    if (apply_act){
        if (t < 64){
            const int half = t >> 5, oo = t & 31;
            const float* pb1 = pin + (size_t)half*16384;
            float S1 = 0.0f, S2 = 0.0f;
            #pragma unroll 8
            for (int i = 0; i < 256; ++i){
                S1 += pb1[i*64 + oo];
                S2 += pb1[i*64 + 32 + oo];
            }
            float mean = S1 * (1.0f/(float)NP);
            float var  = fmaxf(S2 * (1.0f/(float)NP) - mean*mean, 0.0f);
            float sc = g[t] * rsqrtf(var + EPSBN);
            sAff[t]    = sc;
            sAff[64+t] = beta[t] - mean*sc;
            if (affout){ affout[t] = sc; affout[64+t] = sAff[64+t]; }
        }
        __syncthreads();
    }

    float acc[2][32];
    #pragma unroll
    for (int o = 0; o < 32; ++o){
        float bb = bias[obase + o];
        acc[0][o]=bb; acc[1][o]=bb;
    }
    #pragma unroll 4
    for (int c = 0; c < 64; ++c){
        float2 x2 = *(const float2*)(in + (size_t)c*NP + p0);
        float xv[2] = {x2.x, x2.y};
        if (apply_act){
            float sc = sAff[c], sh = sAff[64+c];
            #pragma unroll
            for (int j = 0; j < 2; ++j){
                float v = fmaf(sc, xv[j], sh);
                xv[j] = v >= 0.0f ? v : 0.1f*v;
            }
        }
        const float4* wr = (const float4*)(Wt + c*64 + obase);   // uniform -> s_load
        #pragma unroll
        for (int o4 = 0; o4 < 8; ++o4){
            float4 w = wr[o4];
            #pragma unroll
            for (int j = 0; j < 2; ++j){
                acc[j][4*o4+0] = fmaf(w.x, xv[j], acc[j][4*o4+0]);
                acc[j][4*o4+1] = fmaf(w.y, xv[j], acc[j][4*o4+1]);
                acc[j][4*o4+2] = fmaf(w.z, xv[j], acc[j][4*o4+2]);
                acc[j][4*o4+3] = fmaf(w.w, xv[j], acc[j][4*o4+3]);
            }
        }
    }
    #pragma unroll
    for (int o = 0; o < 32; ++o){
        float2 r = make_float2(acc[0][o], acc[1][o]);
        *(float2*)(out + (size_t)(obase+o)*NP + p0) = r;
    }
    #pragma unroll
    for (int o = 0; o < 32; ++o){
        float a0=acc[0][o], a1=acc[1][o];
        float t1 = wave_sum_f(a0+a1);
        float t2 = wave_sum_f(a0*a0+a1*a1);
        if (lane == 63){ sRed[wv][o] = t1; sRed[wv][32+o] = t2; }
    }
    __syncthreads();
    if (t < 64){
        float v = 0.0f;
        #pragma unroll
        for (int w8 = 0; w8 < 8; ++w8) v += sRed[w8][t];
        pout[(size_t)bo*16384 + bp*64 + t] = v;
    }
}

// ---------------------------------------------------------------------------
// Residual: x2 = leaky(affV(v) + leaky(affY(yt))). affV computed in-kernel
// from partials of v's conv (256 rows/half, 1 row/thread); affY from affx.
// ---------------------------------------------------------------------------
__global__ __launch_bounds__(256,2) void resid_kernel(const float* __restrict__ v,
    const float* __restrict__ yt, float* __restrict__ x2,
    const float* __restrict__ pin, const float* __restrict__ g,
    const float* __restrict__ beta, const float* __restrict__ affY)
{
    __shared__ float sPr[8];
    const int t = threadIdx.x, lane = t & 63, wv = t >> 6;
    const int c = blockIdx.x >> 4;                 // 16 blocks per channel
    {
        const int half = c >> 5, oo = c & 31;
        float a1 = pin[(size_t)half*16384 + t*64 + oo];
        float a2 = pin[(size_t)half*16384 + t*64 + 32 + oo];
        float r1 = wave_sum_f(a1);
        float r2 = wave_sum_f(a2);
        if (lane == 63){ sPr[wv*2] = r1; sPr[wv*2+1] = r2; }
    }
    __syncthreads();
    float S1 = sPr[0]+sPr[2]+sPr[4]+sPr[6];
    float S2 = sPr[1]+sPr[3]+sPr[5]+sPr[7];
    float mean = S1 * (1.0f/(float)NP);
    float var  = fmaxf(S2 * (1.0f/(float)NP) - mean*mean, 0.0f);
    const float va = g[c] * rsqrtf(var + EPSBN);
    const float vb = beta[c] - mean*va;
    const float ya = affY[c], yb = affY[64+c];
    const size_t e0 = (size_t)blockIdx.x*4096 + t;
    #pragma unroll
    for (int i = 0; i < 16; ++i){
        const size_t e = e0 + i*256;
        const float4 vv = ((const float4*)v)[e];
        const float4 yy = ((const float4*)yt)[e];
        float4 r;
        r.x = lrelu(fmaf(va, vv.x, vb) + lrelu(fmaf(ya, yy.x, yb)));
        r.y = lrelu(fmaf(va, vv.y, vb) + lrelu(fmaf(ya, yy.y, yb)));
        r.z = lrelu(fmaf(va, vv.z, vb) + lrelu(fmaf(ya, yy.z, yb)));
        r.w = lrelu(fmaf(va, vv.w, vb) + lrelu(fmaf(ya, yy.w, yb)));
        ((float4*)x2)[e] = r;
    }
}

// ---------------------------------------------------------------------------
// Final: x3 = leaky(aff(v2) + x2); out1[b,c,s] = max_k x3. Aff in-kernel.
// ---------------------------------------------------------------------------
__global__ __launch_bounds__(256,2) void final_kernel(const float* __restrict__ v2,
    const float* __restrict__ x2, const float* __restrict__ pin,
    const float* __restrict__ g, const float* __restrict__ beta,
    float* __restrict__ out1)
{
    __shared__ float sPr[8];
    const int t = threadIdx.x, lane = t & 63, wv = t >> 6;
    const int c = blockIdx.x >> 5;                 // 32 blocks per channel
    {
        const int half = c >> 5, oo = c & 31;
        float a1 = pin[(size_t)half*16384 + t*64 + oo];
        float a2 = pin[(size_t)half*16384 + t*64 + 32 + oo];
        float r1 = wave_sum_f(a1);
        float r2 = wave_sum_f(a2);
        if (lane == 63){ sPr[wv*2] = r1; sPr[wv*2+1] = r2; }
    }
    __syncthreads();
    float S1 = sPr[0]+sPr[2]+sPr[4]+sPr[6];
    float S2 = sPr[1]+sPr[3]+sPr[5]+sPr[7];
    float mean = S1 * (1.0f/(float)NP);
    float var  = fmaxf(S2 * (1.0f/(float)NP) - mean*mean, 0.0f);
    const float a = g[c] * rsqrtf(var + EPSBN);
    const float sh = beta[c] - mean*a;

    const int gg = blockIdx.x*256 + t;
    const int bs = gg & 8191;
    const float4* pv = (const float4*)(v2 + (size_t)c*NP + (size_t)bs*NK);
    const float4* px = (const float4*)(x2 + (size_t)c*NP + (size_t)bs*NK);
    float m = -3.0e38f;
    #pragma unroll
    for (int i = 0; i < 8; ++i){
        float4 av = pv[i], xv = px[i];
        m = fmaxf(m, lrelu(fmaf(a, av.x, sh) + xv.x));
        m = fmaxf(m, lrelu(fmaf(a, av.y, sh) + xv.y));
        m = fmaxf(m, lrelu(fmaf(a, av.z, sh) + xv.z));
        m = fmaxf(m, lrelu(fmaf(a, av.w, sh) + xv.w));
    }
    const int b = bs >> 10, s = bs & 1023;
    out1[((size_t)b*NC + c)*NS + s] = m;
}

// ---------------------------------------------------------------------------
extern "C" void kernel_launch(void* const* d_in, const int* in_sizes, int n_in,
                              void* d_out, int out_size, void* d_ws, size_t ws_size,
                              hipStream_t stream)
{
    const float* xyz      = (const float*)d_in[0];
    const float* features = (const float*)d_in[1];
    const float* w_t    = (const float*)d_in[2];
    const float* w1_0   = (const float*)d_in[3];
    const float* w2_0   = (const float*)d_in[4];
    const float* w1_1   = (const float*)d_in[5];
    const float* w2_1   = (const float*)d_in[6];
    const float* b_t    = (const float*)d_in[7];
    const float* b1_0   = (const float*)d_in[8];
    const float* b2_0   = (const float*)d_in[9];
    const float* b1_1   = (const float*)d_in[10];
    const float* b2_1   = (const float*)d_in[11];
    const float* g_t    = (const float*)d_in[12];
    const float* g1_0   = (const float*)d_in[13];
    const float* g2_0   = (const float*)d_in[14];
    const float* g1_1   = (const float*)d_in[15];
    const float* g2_1   = (const float*)d_in[16];
    const float* beta_t  = (const float*)d_in[17];
    const float* beta1_0 = (const float*)d_in[18];
    const float* beta2_0 = (const float*)d_in[19];
    const float* beta1_1 = (const float*)d_in[20];
    const float* beta2_1 = (const float*)d_in[21];

    float* out = (float*)d_out;

    float* buf0  = (float*)d_ws;
    float* buf1  = buf0 + (size_t)NC*NP;
    float* buf2  = buf1 + (size_t)NC*NP;
    float* nxyz  = buf2 + (size_t)NC*NP;                 // NB*NS*3
    int*   kidx  = (int*)(nxyz + (size_t)NB*NS*3);       // NP ints
    float* pT    = (float*)(kidx + NP);                  // 5 x 32768 partials
    float* p10   = pT  + 32768;
    float* p20   = p10 + 32768;
    float* p11   = p20 + 32768;
    float* p21   = p11 + 32768;
    float* affx  = p21 + 32768;                          // 128 (aff_t for resid)
    float* wt    = affx + 128;                           // 5*4096

    wtrans_kernel<<<5, 256, 0, stream>>>(w_t, w1_0, w2_0, w1_1, w2_1, wt);
    fps_kernel<<<NB, 256, 0, stream>>>(xyz, out, nxyz);
    knn_kernel<<<NQ/4, 256, 0, stream>>>(xyz, nxyz, kidx);

    // stage t: fused gather + conv (features -> buf1, stats pT)
    gconv_kernel<<<512, 512, 0, stream>>>(features, kidx, buf1, wt + 0*4096, b_t, pT);
    // resblock 0
    conv_kernel<<<512, 512, 0, stream>>>(buf1, buf0, wt + 1*4096, b1_0,
                                         pT, g_t, beta_t, affx, p10);
    conv_kernel<<<512, 512, 0, stream>>>(buf0, buf2, wt + 2*4096, b2_0,
                                         p10, g1_0, beta1_0, nullptr, p20);
    resid_kernel<<<1024, 256, 0, stream>>>(buf2, buf1, buf0,
                                           p20, g2_0, beta2_0, affx);
    // resblock 1  (input already activated)
    conv_kernel<<<512, 512, 0, stream>>>(buf0, buf1, wt + 3*4096, b1_1,
                                         nullptr, nullptr, nullptr, nullptr, p11);
    conv_kernel<<<512, 512, 0, stream>>>(buf1, buf2, wt + 4*4096, b2_1,
                                         p11, g1_1, beta1_1, nullptr, p21);
    // epilogue: residual + max over K
    final_kernel<<<2048, 256, 0, stream>>>(buf2, buf0, p21, g2_1, beta2_1,
                                           out + (size_t)NB*3*NS);
}

// Round 9
// 977.971 us; speedup vs baseline: 1.1894x; 1.1187x over previous
//
#include <hip/hip_runtime.h>
#include <stdint.h>

#define NB 8
#define NN 4096
#define NC 64
#define NS 1024
#define NK 32
#define NQ (NB*NS)        /* 8192 queries */
#define NP (NQ*NK)        /* 262144 positions */
#define EPSBN 1e-5f

typedef unsigned long long u64;
typedef unsigned short u16;
typedef float v2f __attribute__((ext_vector_type(2)));
typedef short bf8_t __attribute__((ext_vector_type(8)));    // 8 bf16 (4 VGPRs)
typedef float f4_t __attribute__((ext_vector_type(4)));     // MFMA acc

__device__ __forceinline__ float lrelu(float x){ return x >= 0.0f ? x : 0.1f*x; }

// IEEE-total-order key: ascending key == ascending float
__device__ __forceinline__ unsigned int fkey(float d){
    unsigned int fb = __float_as_uint(d);
    return (fb & 0x80000000u) ? ~fb : (fb | 0x80000000u);
}
// f32 -> bf16 RNE
__device__ __forceinline__ unsigned f2bf(float f){
    unsigned u = __float_as_uint(f);
    return (u + 0x7fffu + ((u >> 16) & 1u)) >> 16;
}
__device__ __forceinline__ float bflo(unsigned u){ return __uint_as_float(u << 16); }
__device__ __forceinline__ float bfhi(unsigned u){ return __uint_as_float(u & 0xffff0000u); }

// inclusive prefix-sum over 64 lanes (ints)
__device__ __forceinline__ int wave_incl_add(int x){
    int v = x;
    {int o=__builtin_amdgcn_update_dpp(0,v,0x111,0xf,0xf,true); v+=o;}
    {int o=__builtin_amdgcn_update_dpp(0,v,0x112,0xf,0xf,true); v+=o;}
    {int o=__builtin_amdgcn_update_dpp(0,v,0x114,0xf,0xf,true); v+=o;}
    {int o=__builtin_amdgcn_update_dpp(0,v,0x118,0xf,0xf,true); v+=o;}
    {int o=__builtin_amdgcn_update_dpp(0,v,0x142,0xa,0xf,true); v+=o;}
    {int o=__builtin_amdgcn_update_dpp(0,v,0x143,0xc,0xf,true); v+=o;}
    return v;
}
// sum within each 16-lane row; valid at lane%16==15
__device__ __forceinline__ float row_sum16(float x){
    int v = __float_as_int(x);
    {int o=__builtin_amdgcn_update_dpp(0,v,0x111,0xf,0xf,true); v=__float_as_int(__int_as_float(v)+__int_as_float(o));}
    {int o=__builtin_amdgcn_update_dpp(0,v,0x112,0xf,0xf,true); v=__float_as_int(__int_as_float(v)+__int_as_float(o));}
    {int o=__builtin_amdgcn_update_dpp(0,v,0x114,0xf,0xf,true); v=__float_as_int(__int_as_float(v)+__int_as_float(o));}
    {int o=__builtin_amdgcn_update_dpp(0,v,0x118,0xf,0xf,true); v=__float_as_int(__int_as_float(v)+__int_as_float(o));}
    return __int_as_float(v);
}
// max-reduce of a packed positive double across the wave, via DPP pairs
__device__ __forceinline__ double wave_max_d(double x){
    int lo = __double2loint(x), hi = __double2hiint(x);
    #define FPS_STG(ctl) { \
        int nl=__builtin_amdgcn_update_dpp(lo,lo,ctl,0xf,0xf,false); \
        int nh=__builtin_amdgcn_update_dpp(hi,hi,ctl,0xf,0xf,false); \
        double mx=fmax(__hiloint2double(hi,lo), __hiloint2double(nh,nl)); \
        lo=__double2loint(mx); hi=__double2hiint(mx); }
    FPS_STG(0x111) FPS_STG(0x112) FPS_STG(0x114) FPS_STG(0x118) FPS_STG(0x142) FPS_STG(0x143)
    #undef FPS_STG
    int flo = __builtin_amdgcn_readlane(lo, 63);
    int fhi = __builtin_amdgcn_readlane(hi, 63);
    return __hiloint2double(fhi, flo);
}

// ---------------------------------------------------------------------------
// FPS (r6/r8 best-measured, 526 us) — unchanged.
// ---------------------------------------------------------------------------
__global__ __launch_bounds__(256,1) void fps_kernel(const float* __restrict__ xyz,
                                                    float* __restrict__ out0,
                                                    float* __restrict__ nxyz)
{
    __shared__ float sX[NN], sY[NN], sZ[NN];
    __shared__ double slots[2][4];
    __shared__ int sFar[NS];
    const int b = blockIdx.x, t = threadIdx.x;
    const int lane = t & 63, wv = t >> 6;
    const float* base = xyz + (size_t)b*NN*3;
    for (int i = t; i < NN; i += 256){
        const float* pp = base + 3*i;
        sX[i] = pp[0]; sY[i] = pp[1]; sZ[i] = pp[2];
    }
    __syncthreads();
    v2f PX[8], PY[8], PZ[8], D[8];
    int LO[16];
    const int pb = t*16;
    #pragma unroll
    for (int j = 0; j < 8; ++j){
        PX[j] = (v2f){ sX[pb+2*j], sX[pb+2*j+1] };
        PY[j] = (v2f){ sY[pb+2*j], sY[pb+2*j+1] };
        PZ[j] = (v2f){ sZ[pb+2*j], sZ[pb+2*j+1] };
        D[j]  = (v2f){ 1e10f, 1e10f };
    }
    #pragma unroll
    for (int j = 0; j < 16; ++j) LO[j] = (int)(~(unsigned)(pb + j));
    int far = 0;
    float cx = sX[0], cy = sY[0], cz = sZ[0];
    for (int s = 0; s < NS; ++s){
        if (t == 255) sFar[s] = far;
        double best;
        {
            #pragma clang fp contract(off)
            v2f cx2 = (v2f){cx, cx}, cy2 = (v2f){cy, cy}, cz2 = (v2f){cz, cz};
            best = -1.0;
            #pragma unroll
            for (int j = 0; j < 8; ++j){
                v2f dx = PX[j] - cx2;
                v2f dy = PY[j] - cy2;
                v2f dz = PZ[j] - cz2;
                v2f dd = (dx*dx + dy*dy) + dz*dz;
                v2f nd = __builtin_elementwise_min(D[j], dd);
                D[j] = nd;
                best = fmax(best, __hiloint2double(__float_as_int(nd.x), LO[2*j]));
                best = fmax(best, __hiloint2double(__float_as_int(nd.y), LO[2*j+1]));
            }
        }
        double wb = wave_max_d(best);
        const int par = s & 1;
        if (lane == 0) slots[par][wv] = wb;
        __syncthreads();
        double s0 = slots[par][0], s1 = slots[par][1];
        double s2 = slots[par][2], s3 = slots[par][3];
        double mm = fmax(fmax(s0, s1), fmax(s2, s3));
        far = (int)(~(unsigned)__double2loint(mm));
        cx = sX[far]; cy = sY[far]; cz = sZ[far];
    }
    __syncthreads();
    for (int s = t; s < NS; s += 256){
        const int f = sFar[s];
        const float x = sX[f], y = sY[f], z = sZ[f];
        float* npq = nxyz + ((size_t)b*NS + s)*3;
        npq[0]=x; npq[1]=y; npq[2]=z;
        out0[(b*3+0)*NS+s]=x; out0[(b*3+1)*NS+s]=y; out0[(b*3+2)*NS+s]=z;
    }
}

// ---------------------------------------------------------------------------
// KNN (unchanged): exact 32nd-smallest via bitwise binary search on fkey.
// ---------------------------------------------------------------------------
__global__ __launch_bounds__(256,2) void knn_kernel(const float* __restrict__ xyz,
                                                    const float* __restrict__ nxyz,
                                                    int* __restrict__ kidx)
{
    const int t = threadIdx.x, lane = t & 63, w = t >> 6;
    const int q = blockIdx.x*4 + w;
    const int b = q >> 10;
    const float* base = xyz + (size_t)b*NN*3;
    const float* qp = nxyz + (size_t)q*3;
    const float qx = qp[0], qy = qp[1], qz = qp[2];
    const float qsq = __fadd_rn(__fadd_rn(__fmul_rn(qx,qx),__fmul_rn(qy,qy)),__fmul_rn(qz,qz));

    unsigned int key[64];
    #pragma unroll
    for (int i = 0; i < 64; ++i){
        const int idx = (i<<6) + lane;
        const float* pp = base + 3*idx;
        float x = pp[0], y = pp[1], z = pp[2];
        float dot = __fadd_rn(__fadd_rn(__fmul_rn(qx,x),__fmul_rn(qy,y)),__fmul_rn(qz,z));
        float psq = __fadd_rn(__fadd_rn(__fmul_rn(x,x),__fmul_rn(y,y)),__fmul_rn(z,z));
        float d = __fadd_rn(__fadd_rn(__fmul_rn(-2.0f,dot),qsq),psq);
        key[i] = fkey(d);
    }
    unsigned int pref = 0; int need = 32;
    for (int bit = 31; bit >= 0; --bit){
        const unsigned int bound = 1u << bit;
        int c = 0;
        #pragma unroll
        for (int i = 0; i < 64; ++i) c += ((key[i] ^ pref) < bound) ? 1 : 0;
        int tot = __builtin_amdgcn_readlane(wave_incl_add(c), 63);
        if (tot < need){ need -= tot; pref |= bound; }
    }
    const unsigned int T = pref;
    int cl = 0;
    #pragma unroll
    for (int i = 0; i < 64; ++i) cl += (key[i] < T) ? 1 : 0;
    int incl_cl = wave_incl_add(cl);
    int clx = incl_cl - cl;
    int tiebase = __builtin_amdgcn_readlane(incl_cl, 63);
    int* oq = kidx + (size_t)q*NK;
    int pos = clx;
    #pragma unroll
    for (int i = 0; i < 64; ++i){
        if (key[i] < T){ oq[pos] = (i<<6) + lane; ++pos; }
    }
    int tcount = 0;
    for (int i = 0; i < 64 && tcount < need; ++i){
        u64 m = __ballot(key[i] == T);
        int myrank = (int)__popcll(m & ((1ull << lane) - 1ull));
        if ((key[i] == T) && (tcount + myrank < need))
            oq[tiebase + tcount + myrank] = (i<<6) + lane;
        tcount += (int)__popcll(m);
    }
}

// ---------------------------------------------------------------------------
// Weight A-frag pack: frag(mt,h)[lane][j] = bf16(W[o=mt*16+(lane&15)]
//                                              [c=h*32+(lane>>4)*8+j])
// 8 frags x 64 lanes x 8 bf16 per matrix (8 KB). 5 matrices.
// ---------------------------------------------------------------------------
__global__ __launch_bounds__(256) void wtrans_kernel(const float* __restrict__ w0,
    const float* __restrict__ w1, const float* __restrict__ w2,
    const float* __restrict__ w3, const float* __restrict__ w4,
    u16* __restrict__ dst)
{
    const float* s;
    switch (blockIdx.x){
        case 0: s = w0; break; case 1: s = w1; break; case 2: s = w2; break;
        case 3: s = w3; break; default: s = w4; break;
    }
    u16* d = dst + (size_t)blockIdx.x*4096;
    for (int i = threadIdx.x; i < 4096; i += 256){
        const int f = i >> 9, lane = (i >> 3) & 63, j = i & 7;
        const int mt = f >> 1, h = f & 1;
        const int o = mt*16 + (lane & 15);
        const int c = h*32 + (lane >> 4)*8 + j;
        d[i] = (u16)f2bf(s[o*64 + c]);
    }
}

// ---------------------------------------------------------------------------
// MFMA conv core. D[m=ch_out][n=pos] = sum_k W[m][k] * act(in[n][k]).
// A = weight frags (packed); B = activation row slices (dwordx4 per khalf).
// D frag: pos = lane&15, ch = mt*16 + (lane>>4)*4 + reg  -> packed dwordx2
// stores, row-major bf16 [p][64]. Stats fused (row16 DPP + LDS + partials).
// ---------------------------------------------------------------------------
template<int ACT>
__global__ __launch_bounds__(256,3) void conv_mfma_kernel(const u16* __restrict__ in,
    u16* __restrict__ out, const u16* __restrict__ wfrag, const float* __restrict__ bias,
    const float* __restrict__ pin, const float* __restrict__ g,
    const float* __restrict__ beta, float* __restrict__ affout,
    float* __restrict__ pout)
{
    __shared__ float sPS[128];
    __shared__ float sAff[128];
    __shared__ float sStat[4*128];
    const int t = threadIdx.x, lane = t & 63, wv = t >> 6;
    const int n = lane & 15, q = lane >> 4;
    const int bb = blockIdx.x;

    if (ACT){
        if (t < 128){
            float S = 0.0f;
            #pragma unroll 8
            for (int r = 0; r < 512; ++r) S += pin[r*128 + t];
            sPS[t] = S;
        }
        __syncthreads();
        if (t < 64){
            float mean = sPS[t] * (1.0f/(float)NP);
            float var  = fmaxf(sPS[64+t] * (1.0f/(float)NP) - mean*mean, 0.0f);
            float sc = g[t] * rsqrtf(var + EPSBN);
            sAff[t]    = sc;
            sAff[64+t] = beta[t] - mean*sc;
            if (affout){ affout[t] = sc; affout[64+t] = sAff[64+t]; }
        }
        __syncthreads();
    }
    // per-lane affine for its fixed k-slices
    float scr[16], shr[16];
    if (ACT){
        #pragma unroll
        for (int h = 0; h < 2; ++h)
            #pragma unroll
            for (int j = 0; j < 8; ++j){
                const int k = h*32 + q*8 + j;
                scr[h*8+j] = sAff[k]; shr[h*8+j] = sAff[64+k];
            }
    }
    // weight frags
    bf8_t wf[8];
    #pragma unroll
    for (int f = 0; f < 8; ++f)
        wf[f] = *(const bf8_t*)(wfrag + (f*64 + lane)*8);
    // bias per (mt, q): 4 consecutive channels
    f4_t bv[4];
    #pragma unroll
    for (int mt = 0; mt < 4; ++mt)
        bv[mt] = *(const f4_t*)(bias + mt*16 + q*4);

    float st1[16], st2[16];
    #pragma unroll
    for (int e = 0; e < 16; ++e){ st1[e] = 0.0f; st2[e] = 0.0f; }

    for (int i = 0; i < 8; ++i){
        const int p0 = bb*512 + wv*128 + i*16;
        const u16* row = in + (size_t)(p0 + n)*64;
        bf8_t bf0, bf1;
        if (ACT){
            union { unsigned u[4]; bf8_t v; } B0, B1;
            uint4 r0 = *(const uint4*)(row + q*8);
            uint4 r1 = *(const uint4*)(row + 32 + q*8);
            const unsigned ra[4] = {r0.x, r0.y, r0.z, r0.w};
            const unsigned rb[4] = {r1.x, r1.y, r1.z, r1.w};
            #pragma unroll
            for (int d = 0; d < 4; ++d){
                float x0 = bflo(ra[d]), x1 = bfhi(ra[d]);
                float y0 = fmaf(scr[2*d],   x0, shr[2*d]);   y0 = lrelu(y0);
                float y1 = fmaf(scr[2*d+1], x1, shr[2*d+1]); y1 = lrelu(y1);
                B0.u[d] = f2bf(y0) | (f2bf(y1) << 16);
                float z0 = bflo(rb[d]), z1 = bfhi(rb[d]);
                float w0 = fmaf(scr[8+2*d],   z0, shr[8+2*d]);   w0 = lrelu(w0);
                float w1 = fmaf(scr[8+2*d+1], z1, shr[8+2*d+1]); w1 = lrelu(w1);
                B1.u[d] = f2bf(w0) | (f2bf(w1) << 16);
            }
            bf0 = B0.v; bf1 = B1.v;
        } else {
            bf0 = *(const bf8_t*)(row + q*8);
            bf1 = *(const bf8_t*)(row + 32 + q*8);
        }
        f4_t acc[4];
        #pragma unroll
        for (int mt = 0; mt < 4; ++mt){
            acc[mt] = (f4_t){0.f,0.f,0.f,0.f};
            acc[mt] = __builtin_amdgcn_mfma_f32_16x16x32_bf16(wf[mt*2+0], bf0, acc[mt], 0,0,0);
            acc[mt] = __builtin_amdgcn_mfma_f32_16x16x32_bf16(wf[mt*2+1], bf1, acc[mt], 0,0,0);
        }
        // epilogue: bias + stats + pack + store (4 x dwordx2, row-major)
        u16* orow = out + (size_t)(p0 + n)*64;
        #pragma unroll
        for (int mt = 0; mt < 4; ++mt){
            float v0 = acc[mt].x + bv[mt].x;
            float v1 = acc[mt].y + bv[mt].y;
            float v2 = acc[mt].z + bv[mt].z;
            float v3 = acc[mt].w + bv[mt].w;
            st1[mt*4+0] += v0; st2[mt*4+0] += v0*v0;
            st1[mt*4+1] += v1; st2[mt*4+1] += v1*v1;
            st1[mt*4+2] += v2; st2[mt*4+2] += v2*v2;
            st1[mt*4+3] += v3; st2[mt*4+3] += v3*v3;
            uint2 pk;
            pk.x = f2bf(v0) | (f2bf(v1) << 16);
            pk.y = f2bf(v2) | (f2bf(v3) << 16);
            *(uint2*)(orow + mt*16 + q*4) = pk;
        }
    }
    // stats: reduce over the 16 positions (lanes within each row-of-16)
    #pragma unroll
    for (int e = 0; e < 16; ++e){
        float r1 = row_sum16(st1[e]);
        float r2 = row_sum16(st2[e]);
        if (n == 15){
            const int ch = (e >> 2)*16 + q*4 + (e & 3);
            sStat[wv*128 + ch]      = r1;
            sStat[wv*128 + 64 + ch] = r2;
        }
    }
    __syncthreads();
    if (t < 128){
        float s = sStat[t] + sStat[128+t] + sStat[256+t] + sStat[384+t];
        pout[(size_t)bb*128 + t] = s;
    }
}

// ---------------------------------------------------------------------------
// Fused gather + conv_t (MFMA): B rows are gathered fp32 feature rows.
// ---------------------------------------------------------------------------
__global__ __launch_bounds__(256,3) void gconv_mfma_kernel(const float* __restrict__ features,
    const int* __restrict__ kidx, u16* __restrict__ out,
    const u16* __restrict__ wfrag, const float* __restrict__ bias,
    float* __restrict__ pout)
{
    __shared__ float sStat[4*128];
    const int t = threadIdx.x, lane = t & 63, wv = t >> 6;
    const int n = lane & 15, q = lane >> 4;
    const int bb = blockIdx.x;

    bf8_t wf[8];
    #pragma unroll
    for (int f = 0; f < 8; ++f)
        wf[f] = *(const bf8_t*)(wfrag + (f*64 + lane)*8);
    f4_t bv[4];
    #pragma unroll
    for (int mt = 0; mt < 4; ++mt)
        bv[mt] = *(const f4_t*)(bias + mt*16 + q*4);

    float st1[16], st2[16];
    #pragma unroll
    for (int e = 0; e < 16; ++e){ st1[e] = 0.0f; st2[e] = 0.0f; }

    for (int i = 0; i < 8; ++i){
        const int p0 = bb*512 + wv*128 + i*16;
        const int p = p0 + n;
        const int b = p >> 15;
        const int idx = kidx[p];
        const float* frow = features + ((size_t)b*NN + idx)*NC;
        union { unsigned u[4]; bf8_t v; } B0, B1;
        {
            float4 a0 = *(const float4*)(frow + q*8);
            float4 a1 = *(const float4*)(frow + q*8 + 4);
            B0.u[0] = f2bf(a0.x) | (f2bf(a0.y) << 16);
            B0.u[1] = f2bf(a0.z) | (f2bf(a0.w) << 16);
            B0.u[2] = f2bf(a1.x) | (f2bf(a1.y) << 16);
            B0.u[3] = f2bf(a1.z) | (f2bf(a1.w) << 16);
            float4 c0 = *(const float4*)(frow + 32 + q*8);
            float4 c1 = *(const float4*)(frow + 32 + q*8 + 4);
            B1.u[0] = f2bf(c0.x) | (f2bf(c0.y) << 16);
            B1.u[1] = f2bf(c0.z) | (f2bf(c0.w) << 16);
            B1.u[2] = f2bf(c1.x) | (f2bf(c1.y) << 16);
            B1.u[3] = f2bf(c1.z) | (f2bf(c1.w) << 16);
        }
        f4_t acc[4];
        #pragma unroll
        for (int mt = 0; mt < 4; ++mt){
            acc[mt] = (f4_t){0.f,0.f,0.f,0.f};
            acc[mt] = __builtin_amdgcn_mfma_f32_16x16x32_bf16(wf[mt*2+0], B0.v, acc[mt], 0,0,0);
            acc[mt] = __builtin_amdgcn_mfma_f32_16x16x32_bf16(wf[mt*2+1], B1.v, acc[mt], 0,0,0);
        }
        u16* orow = out + (size_t)p*64;
        #pragma unroll
        for (int mt = 0; mt < 4; ++mt){
            float v0 = acc[mt].x + bv[mt].x;
            float v1 = acc[mt].y + bv[mt].y;
            float v2 = acc[mt].z + bv[mt].z;
            float v3 = acc[mt].w + bv[mt].w;
            st1[mt*4+0] += v0; st2[mt*4+0] += v0*v0;
            st1[mt*4+1] += v1; st2[mt*4+1] += v1*v1;
            st1[mt*4+2] += v2; st2[mt*4+2] += v2*v2;
            st1[mt*4+3] += v3; st2[mt*4+3] += v3*v3;
            uint2 pk;
            pk.x = f2bf(v0) | (f2bf(v1) << 16);
            pk.y = f2bf(v2) | (f2bf(v3) << 16);
            *(uint2*)(orow + mt*16 + q*4) = pk;
        }
    }
    #pragma unroll
    for (int e = 0; e < 16; ++e){
        float r1 = row_sum16(st1[e]);
        float r2 = row_sum16(st2[e]);
        if (n == 15){
            const int ch = (e >> 2)*16 + q*4 + (e & 3);
            sStat[wv*128 + ch]      = r1;
            sStat[wv*128 + 64 + ch] = r2;
        }
    }
    __syncthreads();
    if (t < 128){
        float s = sStat[t] + sStat[128+t] + sStat[256+t] + sStat[384+t];
        pout[(size_t)bb*128 + t] = s;
    }
}

// ---------------------------------------------------------------------------
// Finalize BN partials -> affine (for resid / final consumers).
// ---------------------------------------------------------------------------
__global__ __launch_bounds__(128) void finalize_kernel(const float* __restrict__ pin,
    const float* __restrict__ g, const float* __restrict__ beta, float* __restrict__ aff)
{
    __shared__ float sPS[128];
    const int t = threadIdx.x;
    float S = 0.0f;
    #pragma unroll 8
    for (int r = 0; r < 512; ++r) S += pin[r*128 + t];
    sPS[t] = S;
    __syncthreads();
    if (t < 64){
        float mean = sPS[t] * (1.0f/(float)NP);
        float var  = fmaxf(sPS[64+t] * (1.0f/(float)NP) - mean*mean, 0.0f);
        float sc = g[t] * rsqrtf(var + EPSBN);
        aff[t]    = sc;
        aff[64+t] = beta[t] - mean*sc;
    }
}

// ---------------------------------------------------------------------------
// Residual (bf16 rows): x2 = leaky(affV(v) + leaky(affY(yt))).
// Column-wise threads: fixed channel pair -> affines in regs, coalesced rows.
// ---------------------------------------------------------------------------
__global__ __launch_bounds__(256,2) void resid_kernel(const u16* __restrict__ v,
    const u16* __restrict__ yt, u16* __restrict__ x2,
    const float* __restrict__ affV, const float* __restrict__ affY)
{
    const int t = threadIdx.x;
    const int dc = t & 31, rg = t >> 5;
    const int c0 = dc*2, c1 = c0 + 1;
    const float va0 = affV[c0], vb0 = affV[64+c0];
    const float va1 = affV[c1], vb1 = affV[64+c1];
    const float ya0 = affY[c0], yb0 = affY[64+c0];
    const float ya1 = affY[c1], yb1 = affY[64+c1];
    const unsigned* vp = (const unsigned*)v;
    const unsigned* yp = (const unsigned*)yt;
    unsigned* xp = (unsigned*)x2;
    const size_t base = (size_t)blockIdx.x*512;
    #pragma unroll 4
    for (int r = rg; r < 512; r += 8){
        const size_t e = (base + r)*32 + dc;
        unsigned uv = vp[e], uy = yp[e];
        float r0 = lrelu(fmaf(va0, bflo(uv), vb0) + lrelu(fmaf(ya0, bflo(uy), yb0)));
        float r1 = lrelu(fmaf(va1, bfhi(uv), vb1) + lrelu(fmaf(ya1, bfhi(uy), yb1)));
        xp[e] = f2bf(r0) | (f2bf(r1) << 16);
    }
}

// ---------------------------------------------------------------------------
// Final: x3 = leaky(aff(v2) + x2); out1[b,c,s] = max over the 32 K-rows.
// ---------------------------------------------------------------------------
__global__ __launch_bounds__(256,2) void final_kernel(const u16* __restrict__ v2,
    const u16* __restrict__ x2, const float* __restrict__ aff,
    float* __restrict__ out1)
{
    const int t = threadIdx.x;
    const int dc = t & 31, sg = t >> 5;
    const int c0 = dc*2, c1 = c0 + 1;
    const float a0 = aff[c0], s0 = aff[64+c0];
    const float a1 = aff[c1], s1 = aff[64+c1];
    const int s = blockIdx.x*8 + sg;
    const unsigned* vp = (const unsigned*)v2;
    const unsigned* xp = (const unsigned*)x2;
    float m0 = -3.0e38f, m1 = -3.0e38f;
    #pragma unroll 8
    for (int kk = 0; kk < 32; ++kk){
        const size_t e = ((size_t)s*32 + kk)*32 + dc;
        unsigned uv = vp[e], ux = xp[e];
        m0 = fmaxf(m0, lrelu(fmaf(a0, bflo(uv), s0) + bflo(ux)));
        m1 = fmaxf(m1, lrelu(fmaf(a1, bfhi(uv), s1) + bfhi(ux)));
    }
    const int b = s >> 10, sl = s & 1023;
    out1[((size_t)b*NC + c0)*NS + sl] = m0;
    out1[((size_t)b*NC + c1)*NS + sl] = m1;
}

// ---------------------------------------------------------------------------
extern "C" void kernel_launch(void* const* d_in, const int* in_sizes, int n_in,
                              void* d_out, int out_size, void* d_ws, size_t ws_size,
                              hipStream_t stream)
{
    const float* xyz      = (const float*)d_in[0];
    const float* features = (const float*)d_in[1];
    const float* w_t    = (const float*)d_in[2];
    const float* w1_0   = (const float*)d_in[3];
    const float* w2_0   = (const float*)d_in[4];
    const float* w1_1   = (const float*)d_in[5];
    const float* w2_1   = (const float*)d_in[6];
    const float* b_t    = (const float*)d_in[7];
    const float* b1_0   = (const float*)d_in[8];
    const float* b2_0   = (const float*)d_in[9];
    const float* b1_1   = (const float*)d_in[10];
    const float* b2_1   = (const float*)d_in[11];
    const float* g_t    = (const float*)d_in[12];
    const float* g1_0   = (const float*)d_in[13];
    const float* g2_0   = (const float*)d_in[14];
    const float* g1_1   = (const float*)d_in[15];
    const float* g2_1   = (const float*)d_in[16];
    const float* beta_t  = (const float*)d_in[17];
    const float* beta1_0 = (const float*)d_in[18];
    const float* beta2_0 = (const float*)d_in[19];
    const float* beta1_1 = (const float*)d_in[20];
    const float* beta2_1 = (const float*)d_in[21];

    float* out = (float*)d_out;

    float* nxyz = (float*)d_ws;                          // 24576 f
    int*   kidx = (int*)(nxyz + 24576);                  // NP ints
    float* pT   = (float*)(kidx + NP);                   // 5 x 512*128 partials
    float* p10  = pT  + 65536;
    float* p20  = p10 + 65536;
    float* p11  = p20 + 65536;
    float* p21  = p11 + 65536;
    float* affT  = p21 + 65536;                          // 128
    float* aff20 = affT + 128;                           // 128
    float* aff21 = aff20 + 128;                          // 128
    u16*  bwt  = (u16*)(aff21 + 128);                    // 5*4096 u16
    u16*  buf0 = bwt + 5*4096;                           // 3 x NP*64 bf16
    u16*  buf1 = buf0 + (size_t)NP*NC;
    u16*  buf2 = buf1 + (size_t)NP*NC;

    wtrans_kernel<<<5, 256, 0, stream>>>(w_t, w1_0, w2_0, w1_1, w2_1, bwt);
    fps_kernel<<<NB, 256, 0, stream>>>(xyz, out, nxyz);
    knn_kernel<<<NQ/4, 256, 0, stream>>>(xyz, nxyz, kidx);

    // conv_t (gather fused) -> buf1, stats pT
    gconv_mfma_kernel<<<512, 256, 0, stream>>>(features, kidx, buf1,
                                               bwt + 0*4096, b_t, pT);
    // resblock 0
    conv_mfma_kernel<1><<<512, 256, 0, stream>>>(buf1, buf0, bwt + 1*4096, b1_0,
                                                 pT, g_t, beta_t, affT, p10);
    conv_mfma_kernel<1><<<512, 256, 0, stream>>>(buf0, buf2, bwt + 2*4096, b2_0,
                                                 p10, g1_0, beta1_0, nullptr, p20);
    finalize_kernel<<<1, 128, 0, stream>>>(p20, g2_0, beta2_0, aff20);
    resid_kernel<<<512, 256, 0, stream>>>(buf2, buf1, buf0, aff20, affT);
    // resblock 1 (input already activated)
    conv_mfma_kernel<0><<<512, 256, 0, stream>>>(buf0, buf1, bwt + 3*4096, b1_1,
                                                 nullptr, nullptr, nullptr, nullptr, p11);
    conv_mfma_kernel<1><<<512, 256, 0, stream>>>(buf1, buf2, bwt + 4*4096, b2_1,
                                                 p11, g1_1, beta1_1, nullptr, p21);
    finalize_kernel<<<1, 128, 0, stream>>>(p21, g2_1, beta2_1, aff21);
    // epilogue: residual + max over K
    final_kernel<<<1024, 256, 0, stream>>>(buf2, buf0, aff21,
                                           out + (size_t)NB*3*NS);
}

// Round 10
// 967.657 us; speedup vs baseline: 1.2021x; 1.0107x over previous
//
#include <hip/hip_runtime.h>
#include <stdint.h>

#define NB 8
#define NN 4096
#define NC 64
#define NS 1024
#define NK 32
#define NQ (NB*NS)        /* 8192 queries */
#define NP (NQ*NK)        /* 262144 positions */
#define EPSBN 1e-5f

typedef unsigned long long u64;
typedef unsigned short u16;
typedef float v2f __attribute__((ext_vector_type(2)));
typedef short bf8_t __attribute__((ext_vector_type(8)));    // 8 bf16 (4 VGPRs)
typedef float f4_t __attribute__((ext_vector_type(4)));     // MFMA acc

__device__ __forceinline__ float lrelu(float x){ return x >= 0.0f ? x : 0.1f*x; }

__device__ __forceinline__ unsigned int fkey(float d){
    unsigned int fb = __float_as_uint(d);
    return (fb & 0x80000000u) ? ~fb : (fb | 0x80000000u);
}
// f32 -> bf16 RNE
__device__ __forceinline__ unsigned f2bf(float f){
    unsigned u = __float_as_uint(f);
    return (u + 0x7fffu + ((u >> 16) & 1u)) >> 16;
}
__device__ __forceinline__ float bflo(unsigned u){ return __uint_as_float(u << 16); }
__device__ __forceinline__ float bfhi(unsigned u){ return __uint_as_float(u & 0xffff0000u); }

// inclusive prefix-sum over 64 lanes (ints)
__device__ __forceinline__ int wave_incl_add(int x){
    int v = x;
    {int o=__builtin_amdgcn_update_dpp(0,v,0x111,0xf,0xf,true); v+=o;}
    {int o=__builtin_amdgcn_update_dpp(0,v,0x112,0xf,0xf,true); v+=o;}
    {int o=__builtin_amdgcn_update_dpp(0,v,0x114,0xf,0xf,true); v+=o;}
    {int o=__builtin_amdgcn_update_dpp(0,v,0x118,0xf,0xf,true); v+=o;}
    {int o=__builtin_amdgcn_update_dpp(0,v,0x142,0xa,0xf,true); v+=o;}
    {int o=__builtin_amdgcn_update_dpp(0,v,0x143,0xc,0xf,true); v+=o;}
    return v;
}
// sum within each 16-lane row; valid at lane%16==15
__device__ __forceinline__ float row_sum16(float x){
    int v = __float_as_int(x);
    {int o=__builtin_amdgcn_update_dpp(0,v,0x111,0xf,0xf,true); v=__float_as_int(__int_as_float(v)+__int_as_float(o));}
    {int o=__builtin_amdgcn_update_dpp(0,v,0x112,0xf,0xf,true); v=__float_as_int(__int_as_float(v)+__int_as_float(o));}
    {int o=__builtin_amdgcn_update_dpp(0,v,0x114,0xf,0xf,true); v=__float_as_int(__int_as_float(v)+__int_as_float(o));}
    {int o=__builtin_amdgcn_update_dpp(0,v,0x118,0xf,0xf,true); v=__float_as_int(__int_as_float(v)+__int_as_float(o));}
    return __int_as_float(v);
}
// max-reduce of a packed positive double across the wave, via DPP pairs
__device__ __forceinline__ double wave_max_d(double x){
    int lo = __double2loint(x), hi = __double2hiint(x);
    #define FPS_STG(ctl) { \
        int nl=__builtin_amdgcn_update_dpp(lo,lo,ctl,0xf,0xf,false); \
        int nh=__builtin_amdgcn_update_dpp(hi,hi,ctl,0xf,0xf,false); \
        double mx=fmax(__hiloint2double(hi,lo), __hiloint2double(nh,nl)); \
        lo=__double2loint(mx); hi=__double2hiint(mx); }
    FPS_STG(0x111) FPS_STG(0x112) FPS_STG(0x114) FPS_STG(0x118) FPS_STG(0x142) FPS_STG(0x143)
    #undef FPS_STG
    int flo = __builtin_amdgcn_readlane(lo, 63);
    int fhi = __builtin_amdgcn_readlane(hi, 63);
    return __hiloint2double(fhi, flo);
}

// ---------------------------------------------------------------------------
// FPS: r6 reduce structure, but 512 thr x 8 pts/thread (A/B on thread count).
// Packed argmax key: double{hi=dist_bits, lo=~idx}; v_max_f64 per point;
// DPP wave reduce; 8 LDS slots, parity double-buffer, 1 barrier/step.
// Bit-exact vs numpy: rn ops, ((dx2+dy2)+dz2), min, first-occurrence.
// ---------------------------------------------------------------------------
__global__ __launch_bounds__(512,1) void fps_kernel(const float* __restrict__ xyz,
                                                    float* __restrict__ out0,
                                                    float* __restrict__ nxyz)
{
    __shared__ float sX[NN], sY[NN], sZ[NN];
    __shared__ double slots[2][8];
    __shared__ int sFar[NS];
    const int b = blockIdx.x, t = threadIdx.x;
    const int lane = t & 63, wv = t >> 6;
    const float* base = xyz + (size_t)b*NN*3;
    for (int i = t; i < NN; i += 512){
        const float* pp = base + 3*i;
        sX[i] = pp[0]; sY[i] = pp[1]; sZ[i] = pp[2];
    }
    __syncthreads();
    v2f PX[4], PY[4], PZ[4], D[4];
    int LO[8];
    const int pb = t*8;
    #pragma unroll
    for (int j = 0; j < 4; ++j){
        PX[j] = (v2f){ sX[pb+2*j], sX[pb+2*j+1] };
        PY[j] = (v2f){ sY[pb+2*j], sY[pb+2*j+1] };
        PZ[j] = (v2f){ sZ[pb+2*j], sZ[pb+2*j+1] };
        D[j]  = (v2f){ 1e10f, 1e10f };
    }
    #pragma unroll
    for (int j = 0; j < 8; ++j) LO[j] = (int)(~(unsigned)(pb + j));
    int far = 0;
    float cx = sX[0], cy = sY[0], cz = sZ[0];
    for (int s = 0; s < NS; ++s){
        if (t == 511) sFar[s] = far;
        double best;
        {
            #pragma clang fp contract(off)
            v2f cx2 = (v2f){cx, cx}, cy2 = (v2f){cy, cy}, cz2 = (v2f){cz, cz};
            best = -1.0;
            #pragma unroll
            for (int j = 0; j < 4; ++j){
                v2f dx = PX[j] - cx2;
                v2f dy = PY[j] - cy2;
                v2f dz = PZ[j] - cz2;
                v2f dd = (dx*dx + dy*dy) + dz*dz;
                v2f nd = __builtin_elementwise_min(D[j], dd);
                D[j] = nd;
                best = fmax(best, __hiloint2double(__float_as_int(nd.x), LO[2*j]));
                best = fmax(best, __hiloint2double(__float_as_int(nd.y), LO[2*j+1]));
            }
        }
        double wb = wave_max_d(best);
        const int par = s & 1;
        if (lane == 0) slots[par][wv] = wb;
        __syncthreads();
        double s0 = slots[par][0], s1 = slots[par][1];
        double s2 = slots[par][2], s3 = slots[par][3];
        double s4 = slots[par][4], s5 = slots[par][5];
        double s6 = slots[par][6], s7 = slots[par][7];
        double mm = fmax(fmax(fmax(s0,s1), fmax(s2,s3)),
                         fmax(fmax(s4,s5), fmax(s6,s7)));
        far = (int)(~(unsigned)__double2loint(mm));
        cx = sX[far]; cy = sY[far]; cz = sZ[far];
    }
    __syncthreads();
    for (int s = t; s < NS; s += 512){
        const int f = sFar[s];
        const float x = sX[f], y = sY[f], z = sZ[f];
        float* npq = nxyz + ((size_t)b*NS + s)*3;
        npq[0]=x; npq[1]=y; npq[2]=z;
        out0[(b*3+0)*NS+s]=x; out0[(b*3+1)*NS+s]=y; out0[(b*3+2)*NS+s]=z;
    }
}

// ---------------------------------------------------------------------------
// KNN (unchanged): exact 32nd-smallest via bitwise binary search on fkey.
// ---------------------------------------------------------------------------
__global__ __launch_bounds__(256,2) void knn_kernel(const float* __restrict__ xyz,
                                                    const float* __restrict__ nxyz,
                                                    int* __restrict__ kidx)
{
    const int t = threadIdx.x, lane = t & 63, w = t >> 6;
    const int q = blockIdx.x*4 + w;
    const int b = q >> 10;
    const float* base = xyz + (size_t)b*NN*3;
    const float* qp = nxyz + (size_t)q*3;
    const float qx = qp[0], qy = qp[1], qz = qp[2];
    const float qsq = __fadd_rn(__fadd_rn(__fmul_rn(qx,qx),__fmul_rn(qy,qy)),__fmul_rn(qz,qz));

    unsigned int key[64];
    #pragma unroll
    for (int i = 0; i < 64; ++i){
        const int idx = (i<<6) + lane;
        const float* pp = base + 3*idx;
        float x = pp[0], y = pp[1], z = pp[2];
        float dot = __fadd_rn(__fadd_rn(__fmul_rn(qx,x),__fmul_rn(qy,y)),__fmul_rn(qz,z));
        float psq = __fadd_rn(__fadd_rn(__fmul_rn(x,x),__fmul_rn(y,y)),__fmul_rn(z,z));
        float d = __fadd_rn(__fadd_rn(__fmul_rn(-2.0f,dot),qsq),psq);
        key[i] = fkey(d);
    }
    unsigned int pref = 0; int need = 32;
    for (int bit = 31; bit >= 0; --bit){
        const unsigned int bound = 1u << bit;
        int c = 0;
        #pragma unroll
        for (int i = 0; i < 64; ++i) c += ((key[i] ^ pref) < bound) ? 1 : 0;
        int tot = __builtin_amdgcn_readlane(wave_incl_add(c), 63);
        if (tot < need){ need -= tot; pref |= bound; }
    }
    const unsigned int T = pref;
    int cl = 0;
    #pragma unroll
    for (int i = 0; i < 64; ++i) cl += (key[i] < T) ? 1 : 0;
    int incl_cl = wave_incl_add(cl);
    int clx = incl_cl - cl;
    int tiebase = __builtin_amdgcn_readlane(incl_cl, 63);
    int* oq = kidx + (size_t)q*NK;
    int pos = clx;
    #pragma unroll
    for (int i = 0; i < 64; ++i){
        if (key[i] < T){ oq[pos] = (i<<6) + lane; ++pos; }
    }
    int tcount = 0;
    for (int i = 0; i < 64 && tcount < need; ++i){
        u64 m = __ballot(key[i] == T);
        int myrank = (int)__popcll(m & ((1ull << lane) - 1ull));
        if ((key[i] == T) && (tcount + myrank < need))
            oq[tiebase + tcount + myrank] = (i<<6) + lane;
        tcount += (int)__popcll(m);
    }
}

// ---------------------------------------------------------------------------
// Weight A-frag pack (unchanged).
// ---------------------------------------------------------------------------
__global__ __launch_bounds__(256) void wtrans_kernel(const float* __restrict__ w0,
    const float* __restrict__ w1, const float* __restrict__ w2,
    const float* __restrict__ w3, const float* __restrict__ w4,
    u16* __restrict__ dst)
{
    const float* s;
    switch (blockIdx.x){
        case 0: s = w0; break; case 1: s = w1; break; case 2: s = w2; break;
        case 3: s = w3; break; default: s = w4; break;
    }
    u16* d = dst + (size_t)blockIdx.x*4096;
    for (int i = threadIdx.x; i < 4096; i += 256){
        const int f = i >> 9, lane = (i >> 3) & 63, j = i & 7;
        const int mt = f >> 1, h = f & 1;
        const int o = mt*16 + (lane & 15);
        const int c = h*32 + (lane >> 4)*8 + j;
        d[i] = (u16)f2bf(s[o*64 + c]);
    }
}

// ---------------------------------------------------------------------------
// Fast BN finalize: 1 block x 1024 thr; 8-way row split + LDS tree.
// pin: [512 rows][128 stats]; aff out: [scale(64), shift(64)].
// ---------------------------------------------------------------------------
__global__ __launch_bounds__(1024) void finalize_kernel(const float* __restrict__ pin,
    const float* __restrict__ g, const float* __restrict__ beta, float* __restrict__ aff)
{
    __shared__ float l1[1024];
    const int t = threadIdx.x;
    const int stat = t & 127, seg = t >> 7;
    float S = 0.0f;
    #pragma unroll 8
    for (int r = seg*64; r < seg*64 + 64; ++r) S += pin[r*128 + stat];
    l1[t] = S;
    __syncthreads();
    if (t < 128){
        float s = l1[t] + l1[128+t] + l1[256+t] + l1[384+t]
                + l1[512+t] + l1[640+t] + l1[768+t] + l1[896+t];
        l1[t] = s;
    }
    __syncthreads();
    if (t < 64){
        float mean = l1[t] * (1.0f/(float)NP);
        float var  = fmaxf(l1[64+t] * (1.0f/(float)NP) - mean*mean, 0.0f);
        float sc = g[t] * rsqrtf(var + EPSBN);
        aff[t]    = sc;
        aff[64+t] = beta[t] - mean*sc;
    }
}

// ---------------------------------------------------------------------------
// MFMA conv core (lean): ACT affine read from aff[] (512 B), no preamble.
// D frag: pos = lane&15, ch = mt*16 + (lane>>4)*4 + reg -> packed dwordx2
// stores, row-major bf16 [p][64]. Stats fused.
// ---------------------------------------------------------------------------
template<int ACT>
__global__ __launch_bounds__(256,3) void conv_mfma_kernel(const u16* __restrict__ in,
    u16* __restrict__ out, const u16* __restrict__ wfrag, const float* __restrict__ bias,
    const float* __restrict__ aff, float* __restrict__ pout)
{
    __shared__ float sStat[4*128];
    const int t = threadIdx.x, lane = t & 63, wv = t >> 6;
    const int n = lane & 15, q = lane >> 4;
    const int bb = blockIdx.x;

    float scr[16], shr[16];
    if (ACT){
        #pragma unroll
        for (int h = 0; h < 2; ++h){
            float4 a0 = *(const float4*)(aff + h*32 + q*8);
            float4 a1 = *(const float4*)(aff + h*32 + q*8 + 4);
            float4 b0 = *(const float4*)(aff + 64 + h*32 + q*8);
            float4 b1 = *(const float4*)(aff + 64 + h*32 + q*8 + 4);
            scr[h*8+0]=a0.x; scr[h*8+1]=a0.y; scr[h*8+2]=a0.z; scr[h*8+3]=a0.w;
            scr[h*8+4]=a1.x; scr[h*8+5]=a1.y; scr[h*8+6]=a1.z; scr[h*8+7]=a1.w;
            shr[h*8+0]=b0.x; shr[h*8+1]=b0.y; shr[h*8+2]=b0.z; shr[h*8+3]=b0.w;
            shr[h*8+4]=b1.x; shr[h*8+5]=b1.y; shr[h*8+6]=b1.z; shr[h*8+7]=b1.w;
        }
    }
    bf8_t wf[8];
    #pragma unroll
    for (int f = 0; f < 8; ++f)
        wf[f] = *(const bf8_t*)(wfrag + (f*64 + lane)*8);
    f4_t bv[4];
    #pragma unroll
    for (int mt = 0; mt < 4; ++mt)
        bv[mt] = *(const f4_t*)(bias + mt*16 + q*4);

    float st1[16], st2[16];
    #pragma unroll
    for (int e = 0; e < 16; ++e){ st1[e] = 0.0f; st2[e] = 0.0f; }

    for (int i = 0; i < 8; ++i){
        const int p0 = bb*512 + wv*128 + i*16;
        const u16* row = in + (size_t)(p0 + n)*64;
        bf8_t bf0, bf1;
        if (ACT){
            union { unsigned u[4]; bf8_t v; } B0, B1;
            uint4 r0 = *(const uint4*)(row + q*8);
            uint4 r1 = *(const uint4*)(row + 32 + q*8);
            const unsigned ra[4] = {r0.x, r0.y, r0.z, r0.w};
            const unsigned rb[4] = {r1.x, r1.y, r1.z, r1.w};
            #pragma unroll
            for (int d = 0; d < 4; ++d){
                float x0 = bflo(ra[d]), x1 = bfhi(ra[d]);
                float y0 = fmaf(scr[2*d],   x0, shr[2*d]);   y0 = lrelu(y0);
                float y1 = fmaf(scr[2*d+1], x1, shr[2*d+1]); y1 = lrelu(y1);
                B0.u[d] = f2bf(y0) | (f2bf(y1) << 16);
                float z0 = bflo(rb[d]), z1 = bfhi(rb[d]);
                float w0 = fmaf(scr[8+2*d],   z0, shr[8+2*d]);   w0 = lrelu(w0);
                float w1 = fmaf(scr[8+2*d+1], z1, shr[8+2*d+1]); w1 = lrelu(w1);
                B1.u[d] = f2bf(w0) | (f2bf(w1) << 16);
            }
            bf0 = B0.v; bf1 = B1.v;
        } else {
            bf0 = *(const bf8_t*)(row + q*8);
            bf1 = *(const bf8_t*)(row + 32 + q*8);
        }
        f4_t acc[4];
        #pragma unroll
        for (int mt = 0; mt < 4; ++mt){
            acc[mt] = (f4_t){0.f,0.f,0.f,0.f};
            acc[mt] = __builtin_amdgcn_mfma_f32_16x16x32_bf16(wf[mt*2+0], bf0, acc[mt], 0,0,0);
            acc[mt] = __builtin_amdgcn_mfma_f32_16x16x32_bf16(wf[mt*2+1], bf1, acc[mt], 0,0,0);
        }
        u16* orow = out + (size_t)(p0 + n)*64;
        #pragma unroll
        for (int mt = 0; mt < 4; ++mt){
            float v0 = acc[mt].x + bv[mt].x;
            float v1 = acc[mt].y + bv[mt].y;
            float v2 = acc[mt].z + bv[mt].z;
            float v3 = acc[mt].w + bv[mt].w;
            st1[mt*4+0] += v0; st2[mt*4+0] += v0*v0;
            st1[mt*4+1] += v1; st2[mt*4+1] += v1*v1;
            st1[mt*4+2] += v2; st2[mt*4+2] += v2*v2;
            st1[mt*4+3] += v3; st2[mt*4+3] += v3*v3;
            uint2 pk;
            pk.x = f2bf(v0) | (f2bf(v1) << 16);
            pk.y = f2bf(v2) | (f2bf(v3) << 16);
            *(uint2*)(orow + mt*16 + q*4) = pk;
        }
    }
    #pragma unroll
    for (int e = 0; e < 16; ++e){
        float r1 = row_sum16(st1[e]);
        float r2 = row_sum16(st2[e]);
        if (n == 15){
            const int ch = (e >> 2)*16 + q*4 + (e & 3);
            sStat[wv*128 + ch]      = r1;
            sStat[wv*128 + 64 + ch] = r2;
        }
    }
    __syncthreads();
    if (t < 128){
        float s = sStat[t] + sStat[128+t] + sStat[256+t] + sStat[384+t];
        pout[(size_t)bb*128 + t] = s;
    }
}

// ---------------------------------------------------------------------------
// Fused gather + conv_t (MFMA) — unchanged from r9.
// ---------------------------------------------------------------------------
__global__ __launch_bounds__(256,3) void gconv_mfma_kernel(const float* __restrict__ features,
    const int* __restrict__ kidx, u16* __restrict__ out,
    const u16* __restrict__ wfrag, const float* __restrict__ bias,
    float* __restrict__ pout)
{
    __shared__ float sStat[4*128];
    const int t = threadIdx.x, lane = t & 63, wv = t >> 6;
    const int n = lane & 15, q = lane >> 4;
    const int bb = blockIdx.x;

    bf8_t wf[8];
    #pragma unroll
    for (int f = 0; f < 8; ++f)
        wf[f] = *(const bf8_t*)(wfrag + (f*64 + lane)*8);
    f4_t bv[4];
    #pragma unroll
    for (int mt = 0; mt < 4; ++mt)
        bv[mt] = *(const f4_t*)(bias + mt*16 + q*4);

    float st1[16], st2[16];
    #pragma unroll
    for (int e = 0; e < 16; ++e){ st1[e] = 0.0f; st2[e] = 0.0f; }

    for (int i = 0; i < 8; ++i){
        const int p0 = bb*512 + wv*128 + i*16;
        const int p = p0 + n;
        const int b = p >> 15;
        const int idx = kidx[p];
        const float* frow = features + ((size_t)b*NN + idx)*NC;
        union { unsigned u[4]; bf8_t v; } B0, B1;
        {
            float4 a0 = *(const float4*)(frow + q*8);
            float4 a1 = *(const float4*)(frow + q*8 + 4);
            B0.u[0] = f2bf(a0.x) | (f2bf(a0.y) << 16);
            B0.u[1] = f2bf(a0.z) | (f2bf(a0.w) << 16);
            B0.u[2] = f2bf(a1.x) | (f2bf(a1.y) << 16);
            B0.u[3] = f2bf(a1.z) | (f2bf(a1.w) << 16);
            float4 c0 = *(const float4*)(frow + 32 + q*8);
            float4 c1 = *(const float4*)(frow + 32 + q*8 + 4);
            B1.u[0] = f2bf(c0.x) | (f2bf(c0.y) << 16);
            B1.u[1] = f2bf(c0.z) | (f2bf(c0.w) << 16);
            B1.u[2] = f2bf(c1.x) | (f2bf(c1.y) << 16);
            B1.u[3] = f2bf(c1.z) | (f2bf(c1.w) << 16);
        }
        f4_t acc[4];
        #pragma unroll
        for (int mt = 0; mt < 4; ++mt){
            acc[mt] = (f4_t){0.f,0.f,0.f,0.f};
            acc[mt] = __builtin_amdgcn_mfma_f32_16x16x32_bf16(wf[mt*2+0], B0.v, acc[mt], 0,0,0);
            acc[mt] = __builtin_amdgcn_mfma_f32_16x16x32_bf16(wf[mt*2+1], B1.v, acc[mt], 0,0,0);
        }
        u16* orow = out + (size_t)p*64;
        #pragma unroll
        for (int mt = 0; mt < 4; ++mt){
            float v0 = acc[mt].x + bv[mt].x;
            float v1 = acc[mt].y + bv[mt].y;
            float v2 = acc[mt].z + bv[mt].z;
            float v3 = acc[mt].w + bv[mt].w;
            st1[mt*4+0] += v0; st2[mt*4+0] += v0*v0;
            st1[mt*4+1] += v1; st2[mt*4+1] += v1*v1;
            st1[mt*4+2] += v2; st2[mt*4+2] += v2*v2;
            st1[mt*4+3] += v3; st2[mt*4+3] += v3*v3;
            uint2 pk;
            pk.x = f2bf(v0) | (f2bf(v1) << 16);
            pk.y = f2bf(v2) | (f2bf(v3) << 16);
            *(uint2*)(orow + mt*16 + q*4) = pk;
        }
    }
    #pragma unroll
    for (int e = 0; e < 16; ++e){
        float r1 = row_sum16(st1[e]);
        float r2 = row_sum16(st2[e]);
        if (n == 15){
            const int ch = (e >> 2)*16 + q*4 + (e & 3);
            sStat[wv*128 + ch]      = r1;
            sStat[wv*128 + 64 + ch] = r2;
        }
    }
    __syncthreads();
    if (t < 128){
        float s = sStat[t] + sStat[128+t] + sStat[256+t] + sStat[384+t];
        pout[(size_t)bb*128 + t] = s;
    }
}

// ---------------------------------------------------------------------------
// Residual (bf16 rows): x2 = leaky(affV(v) + leaky(affY(yt))).
// ---------------------------------------------------------------------------
__global__ __launch_bounds__(256,2) void resid_kernel(const u16* __restrict__ v,
    const u16* __restrict__ yt, u16* __restrict__ x2,
    const float* __restrict__ affV, const float* __restrict__ affY)
{
    const int t = threadIdx.x;
    const int dc = t & 31, rg = t >> 5;
    const int c0 = dc*2, c1 = c0 + 1;
    const float va0 = affV[c0], vb0 = affV[64+c0];
    const float va1 = affV[c1], vb1 = affV[64+c1];
    const float ya0 = affY[c0], yb0 = affY[64+c0];
    const float ya1 = affY[c1], yb1 = affY[64+c1];
    const unsigned* vp = (const unsigned*)v;
    const unsigned* yp = (const unsigned*)yt;
    unsigned* xp = (unsigned*)x2;
    const size_t base = (size_t)blockIdx.x*512;
    #pragma unroll 4
    for (int r = rg; r < 512; r += 8){
        const size_t e = (base + r)*32 + dc;
        unsigned uv = vp[e], uy = yp[e];
        float r0 = lrelu(fmaf(va0, bflo(uv), vb0) + lrelu(fmaf(ya0, bflo(uy), yb0)));
        float r1 = lrelu(fmaf(va1, bfhi(uv), vb1) + lrelu(fmaf(ya1, bfhi(uy), yb1)));
        xp[e] = f2bf(r0) | (f2bf(r1) << 16);
    }
}

// ---------------------------------------------------------------------------
// Final: x3 = leaky(aff(v2) + x2); out1[b,c,s] = max over the 32 K-rows.
// ---------------------------------------------------------------------------
__global__ __launch_bounds__(256,2) void final_kernel(const u16* __restrict__ v2,
    const u16* __restrict__ x2, const float* __restrict__ aff,
    float* __restrict__ out1)
{
    const int t = threadIdx.x;
    const int dc = t & 31, sg = t >> 5;
    const int c0 = dc*2, c1 = c0 + 1;
    const float a0 = aff[c0], s0 = aff[64+c0];
    const float a1 = aff[c1], s1 = aff[64+c1];
    const int s = blockIdx.x*8 + sg;
    const unsigned* vp = (const unsigned*)v2;
    const unsigned* xp = (const unsigned*)x2;
    float m0 = -3.0e38f, m1 = -3.0e38f;
    #pragma unroll 8
    for (int kk = 0; kk < 32; ++kk){
        const size_t e = ((size_t)s*32 + kk)*32 + dc;
        unsigned uv = vp[e], ux = xp[e];
        m0 = fmaxf(m0, lrelu(fmaf(a0, bflo(uv), s0) + bflo(ux)));
        m1 = fmaxf(m1, lrelu(fmaf(a1, bfhi(uv), s1) + bfhi(ux)));
    }
    const int b = s >> 10, sl = s & 1023;
    out1[((size_t)b*NC + c0)*NS + sl] = m0;
    out1[((size_t)b*NC + c1)*NS + sl] = m1;
}

// ---------------------------------------------------------------------------
extern "C" void kernel_launch(void* const* d_in, const int* in_sizes, int n_in,
                              void* d_out, int out_size, void* d_ws, size_t ws_size,
                              hipStream_t stream)
{
    const float* xyz      = (const float*)d_in[0];
    const float* features = (const float*)d_in[1];
    const float* w_t    = (const float*)d_in[2];
    const float* w1_0   = (const float*)d_in[3];
    const float* w2_0   = (const float*)d_in[4];
    const float* w1_1   = (const float*)d_in[5];
    const float* w2_1   = (const float*)d_in[6];
    const float* b_t    = (const float*)d_in[7];
    const float* b1_0   = (const float*)d_in[8];
    const float* b2_0   = (const float*)d_in[9];
    const float* b1_1   = (const float*)d_in[10];
    const float* b2_1   = (const float*)d_in[11];
    const float* g_t    = (const float*)d_in[12];
    const float* g1_0   = (const float*)d_in[13];
    const float* g2_0   = (const float*)d_in[14];
    const float* g1_1   = (const float*)d_in[15];
    const float* g2_1   = (const float*)d_in[16];
    const float* beta_t  = (const float*)d_in[17];
    const float* beta1_0 = (const float*)d_in[18];
    const float* beta2_0 = (const float*)d_in[19];
    const float* beta1_1 = (const float*)d_in[20];
    const float* beta2_1 = (const float*)d_in[21];

    float* out = (float*)d_out;

    float* nxyz = (float*)d_ws;                          // 24576 f
    int*   kidx = (int*)(nxyz + 24576);                  // NP ints
    float* pT   = (float*)(kidx + NP);                   // 5 x 512*128 partials
    float* p10  = pT  + 65536;
    float* p20  = p10 + 65536;
    float* p11  = p20 + 65536;
    float* p21  = p11 + 65536;
    float* affT  = p21 + 65536;                          // 5 x 128
    float* aff10 = affT + 128;
    float* aff20 = aff10 + 128;
    float* aff11 = aff20 + 128;
    float* aff21 = aff11 + 128;
    u16*  bwt  = (u16*)(aff21 + 128);                    // 5*4096 u16
    u16*  buf0 = bwt + 5*4096;                           // 3 x NP*64 bf16
    u16*  buf1 = buf0 + (size_t)NP*NC;
    u16*  buf2 = buf1 + (size_t)NP*NC;

    wtrans_kernel<<<5, 256, 0, stream>>>(w_t, w1_0, w2_0, w1_1, w2_1, bwt);
    fps_kernel<<<NB, 512, 0, stream>>>(xyz, out, nxyz);
    knn_kernel<<<NQ/4, 256, 0, stream>>>(xyz, nxyz, kidx);

    // conv_t (gather fused) -> buf1, stats pT
    gconv_mfma_kernel<<<512, 256, 0, stream>>>(features, kidx, buf1,
                                               bwt + 0*4096, b_t, pT);
    finalize_kernel<<<1, 1024, 0, stream>>>(pT, g_t, beta_t, affT);
    // resblock 0
    conv_mfma_kernel<1><<<512, 256, 0, stream>>>(buf1, buf0, bwt + 1*4096, b1_0,
                                                 affT, p10);
    finalize_kernel<<<1, 1024, 0, stream>>>(p10, g1_0, beta1_0, aff10);
    conv_mfma_kernel<1><<<512, 256, 0, stream>>>(buf0, buf2, bwt + 2*4096, b2_0,
                                                 aff10, p20);
    finalize_kernel<<<1, 1024, 0, stream>>>(p20, g2_0, beta2_0, aff20);
    resid_kernel<<<512, 256, 0, stream>>>(buf2, buf1, buf0, aff20, affT);
    // resblock 1 (input already activated)
    conv_mfma_kernel<0><<<512, 256, 0, stream>>>(buf0, buf1, bwt + 3*4096, b1_1,
                                                 nullptr, p11);
    finalize_kernel<<<1, 1024, 0, stream>>>(p11, g1_1, beta1_1, aff11);
    conv_mfma_kernel<1><<<512, 256, 0, stream>>>(buf1, buf2, bwt + 4*4096, b2_1,
                                                 aff11, p21);
    finalize_kernel<<<1, 1024, 0, stream>>>(p21, g2_1, beta2_1, aff21);
    // epilogue: residual + max over K
    final_kernel<<<1024, 256, 0, stream>>>(buf2, buf0, aff21,
                                           out + (size_t)NB*3*NS);
}

// Round 11
// 927.174 us; speedup vs baseline: 1.2546x; 1.0437x over previous
//
#include <hip/hip_runtime.h>
#include <stdint.h>

#define NB 8
#define NN 4096
#define NC 64
#define NS 1024
#define NK 32
#define NQ (NB*NS)        /* 8192 queries */
#define NP (NQ*NK)        /* 262144 positions */
#define EPSBN 1e-5f

typedef unsigned long long u64;
typedef unsigned short u16;
typedef float v2f __attribute__((ext_vector_type(2)));
typedef short bf8_t __attribute__((ext_vector_type(8)));    // 8 bf16 (4 VGPRs)
typedef float f4_t __attribute__((ext_vector_type(4)));     // MFMA acc

__device__ __forceinline__ float lrelu(float x){ return x >= 0.0f ? x : 0.1f*x; }

__device__ __forceinline__ unsigned int fkey(float d){
    unsigned int fb = __float_as_uint(d);
    return (fb & 0x80000000u) ? ~fb : (fb | 0x80000000u);
}
// f32 -> bf16 RNE
__device__ __forceinline__ unsigned f2bf(float f){
    unsigned u = __float_as_uint(f);
    return (u + 0x7fffu + ((u >> 16) & 1u)) >> 16;
}
__device__ __forceinline__ float bflo(unsigned u){ return __uint_as_float(u << 16); }
__device__ __forceinline__ float bfhi(unsigned u){ return __uint_as_float(u & 0xffff0000u); }

// inclusive prefix-sum over 64 lanes (ints)
__device__ __forceinline__ int wave_incl_add(int x){
    int v = x;
    {int o=__builtin_amdgcn_update_dpp(0,v,0x111,0xf,0xf,true); v+=o;}
    {int o=__builtin_amdgcn_update_dpp(0,v,0x112,0xf,0xf,true); v+=o;}
    {int o=__builtin_amdgcn_update_dpp(0,v,0x114,0xf,0xf,true); v+=o;}
    {int o=__builtin_amdgcn_update_dpp(0,v,0x118,0xf,0xf,true); v+=o;}
    {int o=__builtin_amdgcn_update_dpp(0,v,0x142,0xa,0xf,true); v+=o;}
    {int o=__builtin_amdgcn_update_dpp(0,v,0x143,0xc,0xf,true); v+=o;}
    return v;
}
// sum within each 16-lane row; valid at lane%16==15
__device__ __forceinline__ float row_sum16(float x){
    int v = __float_as_int(x);
    {int o=__builtin_amdgcn_update_dpp(0,v,0x111,0xf,0xf,true); v=__float_as_int(__int_as_float(v)+__int_as_float(o));}
    {int o=__builtin_amdgcn_update_dpp(0,v,0x112,0xf,0xf,true); v=__float_as_int(__int_as_float(v)+__int_as_float(o));}
    {int o=__builtin_amdgcn_update_dpp(0,v,0x114,0xf,0xf,true); v=__float_as_int(__int_as_float(v)+__int_as_float(o));}
    {int o=__builtin_amdgcn_update_dpp(0,v,0x118,0xf,0xf,true); v=__float_as_int(__int_as_float(v)+__int_as_float(o));}
    return __int_as_float(v);
}
// max-reduce of a packed positive double across the wave, via DPP pairs
__device__ __forceinline__ double wave_max_d(double x){
    int lo = __double2loint(x), hi = __double2hiint(x);
    #define FPS_STG(ctl) { \
        int nl=__builtin_amdgcn_update_dpp(lo,lo,ctl,0xf,0xf,false); \
        int nh=__builtin_amdgcn_update_dpp(hi,hi,ctl,0xf,0xf,false); \
        double mx=fmax(__hiloint2double(hi,lo), __hiloint2double(nh,nl)); \
        lo=__double2loint(mx); hi=__double2hiint(mx); }
    FPS_STG(0x111) FPS_STG(0x112) FPS_STG(0x114) FPS_STG(0x118) FPS_STG(0x142) FPS_STG(0x143)
    #undef FPS_STG
    int flo = __builtin_amdgcn_readlane(lo, 63);
    int fhi = __builtin_amdgcn_readlane(hi, 63);
    return __hiloint2double(fhi, flo);
}

// ---------------------------------------------------------------------------
// FPS (r6/r8 best-measured, 523-526 us): 256 thr, 16 pts/thread, v2f update,
// per-point packed f64 argmax key {dist_bits, ~idx}; DPP wave reduce; 4 LDS
// slots. Bit-exact vs numpy: rn ops, ((dx2+dy2)+dz2), min, first-occurrence.
// NOTE r10 A/B: 512 thr x 8 pts = 571 us (regression) -> keep 256 thr.
// ---------------------------------------------------------------------------
__global__ __launch_bounds__(256,1) void fps_kernel(const float* __restrict__ xyz,
                                                    float* __restrict__ out0,
                                                    float* __restrict__ nxyz)
{
    __shared__ float sX[NN], sY[NN], sZ[NN];
    __shared__ double slots[2][4];
    __shared__ int sFar[NS];
    const int b = blockIdx.x, t = threadIdx.x;
    const int lane = t & 63, wv = t >> 6;
    const float* base = xyz + (size_t)b*NN*3;
    for (int i = t; i < NN; i += 256){
        const float* pp = base + 3*i;
        sX[i] = pp[0]; sY[i] = pp[1]; sZ[i] = pp[2];
    }
    __syncthreads();
    v2f PX[8], PY[8], PZ[8], D[8];
    int LO[16];
    const int pb = t*16;
    #pragma unroll
    for (int j = 0; j < 8; ++j){
        PX[j] = (v2f){ sX[pb+2*j], sX[pb+2*j+1] };
        PY[j] = (v2f){ sY[pb+2*j], sY[pb+2*j+1] };
        PZ[j] = (v2f){ sZ[pb+2*j], sZ[pb+2*j+1] };
        D[j]  = (v2f){ 1e10f, 1e10f };
    }
    #pragma unroll
    for (int j = 0; j < 16; ++j) LO[j] = (int)(~(unsigned)(pb + j));
    int far = 0;
    float cx = sX[0], cy = sY[0], cz = sZ[0];
    for (int s = 0; s < NS; ++s){
        if (t == 255) sFar[s] = far;
        double best;
        {
            #pragma clang fp contract(off)
            v2f cx2 = (v2f){cx, cx}, cy2 = (v2f){cy, cy}, cz2 = (v2f){cz, cz};
            best = -1.0;
            #pragma unroll
            for (int j = 0; j < 8; ++j){
                v2f dx = PX[j] - cx2;
                v2f dy = PY[j] - cy2;
                v2f dz = PZ[j] - cz2;
                v2f dd = (dx*dx + dy*dy) + dz*dz;
                v2f nd = __builtin_elementwise_min(D[j], dd);
                D[j] = nd;
                best = fmax(best, __hiloint2double(__float_as_int(nd.x), LO[2*j]));
                best = fmax(best, __hiloint2double(__float_as_int(nd.y), LO[2*j+1]));
            }
        }
        double wb = wave_max_d(best);
        const int par = s & 1;
        if (lane == 0) slots[par][wv] = wb;
        __syncthreads();
        double s0 = slots[par][0], s1 = slots[par][1];
        double s2 = slots[par][2], s3 = slots[par][3];
        double mm = fmax(fmax(s0, s1), fmax(s2, s3));
        far = (int)(~(unsigned)__double2loint(mm));
        cx = sX[far]; cy = sY[far]; cz = sZ[far];
    }
    __syncthreads();
    for (int s = t; s < NS; s += 256){
        const int f = sFar[s];
        const float x = sX[f], y = sY[f], z = sZ[f];
        float* npq = nxyz + ((size_t)b*NS + s)*3;
        npq[0]=x; npq[1]=y; npq[2]=z;
        out0[(b*3+0)*NS+s]=x; out0[(b*3+1)*NS+s]=y; out0[(b*3+2)*NS+s]=z;
    }
}

// ---------------------------------------------------------------------------
// KNN (unchanged): exact 32nd-smallest via bitwise binary search on fkey.
// ---------------------------------------------------------------------------
__global__ __launch_bounds__(256,2) void knn_kernel(const float* __restrict__ xyz,
                                                    const float* __restrict__ nxyz,
                                                    int* __restrict__ kidx)
{
    const int t = threadIdx.x, lane = t & 63, w = t >> 6;
    const int q = blockIdx.x*4 + w;
    const int b = q >> 10;
    const float* base = xyz + (size_t)b*NN*3;
    const float* qp = nxyz + (size_t)q*3;
    const float qx = qp[0], qy = qp[1], qz = qp[2];
    const float qsq = __fadd_rn(__fadd_rn(__fmul_rn(qx,qx),__fmul_rn(qy,qy)),__fmul_rn(qz,qz));

    unsigned int key[64];
    #pragma unroll
    for (int i = 0; i < 64; ++i){
        const int idx = (i<<6) + lane;
        const float* pp = base + 3*idx;
        float x = pp[0], y = pp[1], z = pp[2];
        float dot = __fadd_rn(__fadd_rn(__fmul_rn(qx,x),__fmul_rn(qy,y)),__fmul_rn(qz,z));
        float psq = __fadd_rn(__fadd_rn(__fmul_rn(x,x),__fmul_rn(y,y)),__fmul_rn(z,z));
        float d = __fadd_rn(__fadd_rn(__fmul_rn(-2.0f,dot),qsq),psq);
        key[i] = fkey(d);
    }
    unsigned int pref = 0; int need = 32;
    for (int bit = 31; bit >= 0; --bit){
        const unsigned int bound = 1u << bit;
        int c = 0;
        #pragma unroll
        for (int i = 0; i < 64; ++i) c += ((key[i] ^ pref) < bound) ? 1 : 0;
        int tot = __builtin_amdgcn_readlane(wave_incl_add(c), 63);
        if (tot < need){ need -= tot; pref |= bound; }
    }
    const unsigned int T = pref;
    int cl = 0;
    #pragma unroll
    for (int i = 0; i < 64; ++i) cl += (key[i] < T) ? 1 : 0;
    int incl_cl = wave_incl_add(cl);
    int clx = incl_cl - cl;
    int tiebase = __builtin_amdgcn_readlane(incl_cl, 63);
    int* oq = kidx + (size_t)q*NK;
    int pos = clx;
    #pragma unroll
    for (int i = 0; i < 64; ++i){
        if (key[i] < T){ oq[pos] = (i<<6) + lane; ++pos; }
    }
    int tcount = 0;
    for (int i = 0; i < 64 && tcount < need; ++i){
        u64 m = __ballot(key[i] == T);
        int myrank = (int)__popcll(m & ((1ull << lane) - 1ull));
        if ((key[i] == T) && (tcount + myrank < need))
            oq[tiebase + tcount + myrank] = (i<<6) + lane;
        tcount += (int)__popcll(m);
    }
}

// ---------------------------------------------------------------------------
// Weight A-frag pack (unchanged).
// ---------------------------------------------------------------------------
__global__ __launch_bounds__(256) void wtrans_kernel(const float* __restrict__ w0,
    const float* __restrict__ w1, const float* __restrict__ w2,
    const float* __restrict__ w3, const float* __restrict__ w4,
    u16* __restrict__ dst)
{
    const float* s;
    switch (blockIdx.x){
        case 0: s = w0; break; case 1: s = w1; break; case 2: s = w2; break;
        case 3: s = w3; break; default: s = w4; break;
    }
    u16* d = dst + (size_t)blockIdx.x*4096;
    for (int i = threadIdx.x; i < 4096; i += 256){
        const int f = i >> 9, lane = (i >> 3) & 63, j = i & 7;
        const int mt = f >> 1, h = f & 1;
        const int o = mt*16 + (lane & 15);
        const int c = h*32 + (lane >> 4)*8 + j;
        d[i] = (u16)f2bf(s[o*64 + c]);
    }
}

// ---------------------------------------------------------------------------
// Fast BN finalize: 1 block x 1024 thr; 8-way row split + LDS tree.
// pin: [1024 rows][128 stats]; aff out: [scale(64), shift(64)].
// ---------------------------------------------------------------------------
__global__ __launch_bounds__(1024) void finalize_kernel(const float* __restrict__ pin,
    const float* __restrict__ g, const float* __restrict__ beta, float* __restrict__ aff)
{
    __shared__ float l1[1024];
    const int t = threadIdx.x;
    const int stat = t & 127, seg = t >> 7;
    float S = 0.0f;
    #pragma unroll 8
    for (int r = seg*128; r < seg*128 + 128; ++r) S += pin[r*128 + stat];
    l1[t] = S;
    __syncthreads();
    if (t < 128){
        float s = l1[t] + l1[128+t] + l1[256+t] + l1[384+t]
                + l1[512+t] + l1[640+t] + l1[768+t] + l1[896+t];
        l1[t] = s;
    }
    __syncthreads();
    if (t < 64){
        float mean = l1[t] * (1.0f/(float)NP);
        float var  = fmaxf(l1[64+t] * (1.0f/(float)NP) - mean*mean, 0.0f);
        float sc = g[t] * rsqrtf(var + EPSBN);
        aff[t]    = sc;
        aff[64+t] = beta[t] - mean*sc;
    }
}

// ---------------------------------------------------------------------------
// MFMA conv core: grid 1024 (3 blocks/CU resident), 4 iters fully unrolled
// so all loads issue up-front. ACT affine from aff[] (512 B).
// D frag: pos = lane&15, ch = mt*16 + (lane>>4)*4 + reg -> packed dwordx2
// stores, row-major bf16 [p][64]. Stats fused.
// ---------------------------------------------------------------------------
template<int ACT>
__global__ __launch_bounds__(256,3) void conv_mfma_kernel(const u16* __restrict__ in,
    u16* __restrict__ out, const u16* __restrict__ wfrag, const float* __restrict__ bias,
    const float* __restrict__ aff, float* __restrict__ pout)
{
    __shared__ float sStat[4*128];
    const int t = threadIdx.x, lane = t & 63, wv = t >> 6;
    const int n = lane & 15, q = lane >> 4;
    const int bb = blockIdx.x;

    float scr[16], shr[16];
    if (ACT){
        #pragma unroll
        for (int h = 0; h < 2; ++h){
            float4 a0 = *(const float4*)(aff + h*32 + q*8);
            float4 a1 = *(const float4*)(aff + h*32 + q*8 + 4);
            float4 b0 = *(const float4*)(aff + 64 + h*32 + q*8);
            float4 b1 = *(const float4*)(aff + 64 + h*32 + q*8 + 4);
            scr[h*8+0]=a0.x; scr[h*8+1]=a0.y; scr[h*8+2]=a0.z; scr[h*8+3]=a0.w;
            scr[h*8+4]=a1.x; scr[h*8+5]=a1.y; scr[h*8+6]=a1.z; scr[h*8+7]=a1.w;
            shr[h*8+0]=b0.x; shr[h*8+1]=b0.y; shr[h*8+2]=b0.z; shr[h*8+3]=b0.w;
            shr[h*8+4]=b1.x; shr[h*8+5]=b1.y; shr[h*8+6]=b1.z; shr[h*8+7]=b1.w;
        }
    }
    bf8_t wf[8];
    #pragma unroll
    for (int f = 0; f < 8; ++f)
        wf[f] = *(const bf8_t*)(wfrag + (f*64 + lane)*8);
    f4_t bv[4];
    #pragma unroll
    for (int mt = 0; mt < 4; ++mt)
        bv[mt] = *(const f4_t*)(bias + mt*16 + q*4);

    float st1[16], st2[16];
    #pragma unroll
    for (int e = 0; e < 16; ++e){ st1[e] = 0.0f; st2[e] = 0.0f; }

    #pragma unroll
    for (int i = 0; i < 4; ++i){
        const int p0 = bb*256 + wv*64 + i*16;
        const u16* row = in + (size_t)(p0 + n)*64;
        bf8_t bf0, bf1;
        if (ACT){
            union { unsigned u[4]; bf8_t v; } B0, B1;
            uint4 r0 = *(const uint4*)(row + q*8);
            uint4 r1 = *(const uint4*)(row + 32 + q*8);
            const unsigned ra[4] = {r0.x, r0.y, r0.z, r0.w};
            const unsigned rb[4] = {r1.x, r1.y, r1.z, r1.w};
            #pragma unroll
            for (int d = 0; d < 4; ++d){
                float x0 = bflo(ra[d]), x1 = bfhi(ra[d]);
                float y0 = fmaf(scr[2*d],   x0, shr[2*d]);   y0 = lrelu(y0);
                float y1 = fmaf(scr[2*d+1], x1, shr[2*d+1]); y1 = lrelu(y1);
                B0.u[d] = f2bf(y0) | (f2bf(y1) << 16);
                float z0 = bflo(rb[d]), z1 = bfhi(rb[d]);
                float w0 = fmaf(scr[8+2*d],   z0, shr[8+2*d]);   w0 = lrelu(w0);
                float w1 = fmaf(scr[8+2*d+1], z1, shr[8+2*d+1]); w1 = lrelu(w1);
                B1.u[d] = f2bf(w0) | (f2bf(w1) << 16);
            }
            bf0 = B0.v; bf1 = B1.v;
        } else {
            bf0 = *(const bf8_t*)(row + q*8);
            bf1 = *(const bf8_t*)(row + 32 + q*8);
        }
        f4_t acc[4];
        #pragma unroll
        for (int mt = 0; mt < 4; ++mt){
            acc[mt] = (f4_t){0.f,0.f,0.f,0.f};
            acc[mt] = __builtin_amdgcn_mfma_f32_16x16x32_bf16(wf[mt*2+0], bf0, acc[mt], 0,0,0);
            acc[mt] = __builtin_amdgcn_mfma_f32_16x16x32_bf16(wf[mt*2+1], bf1, acc[mt], 0,0,0);
        }
        u16* orow = out + (size_t)(p0 + n)*64;
        #pragma unroll
        for (int mt = 0; mt < 4; ++mt){
            float v0 = acc[mt].x + bv[mt].x;
            float v1 = acc[mt].y + bv[mt].y;
            float v2 = acc[mt].z + bv[mt].z;
            float v3 = acc[mt].w + bv[mt].w;
            st1[mt*4+0] += v0; st2[mt*4+0] += v0*v0;
            st1[mt*4+1] += v1; st2[mt*4+1] += v1*v1;
            st1[mt*4+2] += v2; st2[mt*4+2] += v2*v2;
            st1[mt*4+3] += v3; st2[mt*4+3] += v3*v3;
            uint2 pk;
            pk.x = f2bf(v0) | (f2bf(v1) << 16);
            pk.y = f2bf(v2) | (f2bf(v3) << 16);
            *(uint2*)(orow + mt*16 + q*4) = pk;
        }
    }
    #pragma unroll
    for (int e = 0; e < 16; ++e){
        float r1 = row_sum16(st1[e]);
        float r2 = row_sum16(st2[e]);
        if (n == 15){
            const int ch = (e >> 2)*16 + q*4 + (e & 3);
            sStat[wv*128 + ch]      = r1;
            sStat[wv*128 + 64 + ch] = r2;
        }
    }
    __syncthreads();
    if (t < 128){
        float s = sStat[t] + sStat[128+t] + sStat[256+t] + sStat[384+t];
        pout[(size_t)bb*128 + t] = s;
    }
}

// ---------------------------------------------------------------------------
// Fused gather + conv_t (MFMA): grid 1024, 4 iters unrolled.
// ---------------------------------------------------------------------------
__global__ __launch_bounds__(256,3) void gconv_mfma_kernel(const float* __restrict__ features,
    const int* __restrict__ kidx, u16* __restrict__ out,
    const u16* __restrict__ wfrag, const float* __restrict__ bias,
    float* __restrict__ pout)
{
    __shared__ float sStat[4*128];
    const int t = threadIdx.x, lane = t & 63, wv = t >> 6;
    const int n = lane & 15, q = lane >> 4;
    const int bb = blockIdx.x;

    bf8_t wf[8];
    #pragma unroll
    for (int f = 0; f < 8; ++f)
        wf[f] = *(const bf8_t*)(wfrag + (f*64 + lane)*8);
    f4_t bv[4];
    #pragma unroll
    for (int mt = 0; mt < 4; ++mt)
        bv[mt] = *(const f4_t*)(bias + mt*16 + q*4);

    float st1[16], st2[16];
    #pragma unroll
    for (int e = 0; e < 16; ++e){ st1[e] = 0.0f; st2[e] = 0.0f; }

    #pragma unroll
    for (int i = 0; i < 4; ++i){
        const int p0 = bb*256 + wv*64 + i*16;
        const int p = p0 + n;
        const int b = p >> 15;
        const int idx = kidx[p];
        const float* frow = features + ((size_t)b*NN + idx)*NC;
        union { unsigned u[4]; bf8_t v; } B0, B1;
        {
            float4 a0 = *(const float4*)(frow + q*8);
            float4 a1 = *(const float4*)(frow + q*8 + 4);
            B0.u[0] = f2bf(a0.x) | (f2bf(a0.y) << 16);
            B0.u[1] = f2bf(a0.z) | (f2bf(a0.w) << 16);
            B0.u[2] = f2bf(a1.x) | (f2bf(a1.y) << 16);
            B0.u[3] = f2bf(a1.z) | (f2bf(a1.w) << 16);
            float4 c0 = *(const float4*)(frow + 32 + q*8);
            float4 c1 = *(const float4*)(frow + 32 + q*8 + 4);
            B1.u[0] = f2bf(c0.x) | (f2bf(c0.y) << 16);
            B1.u[1] = f2bf(c0.z) | (f2bf(c0.w) << 16);
            B1.u[2] = f2bf(c1.x) | (f2bf(c1.y) << 16);
            B1.u[3] = f2bf(c1.z) | (f2bf(c1.w) << 16);
        }
        f4_t acc[4];
        #pragma unroll
        for (int mt = 0; mt < 4; ++mt){
            acc[mt] = (f4_t){0.f,0.f,0.f,0.f};
            acc[mt] = __builtin_amdgcn_mfma_f32_16x16x32_bf16(wf[mt*2+0], B0.v, acc[mt], 0,0,0);
            acc[mt] = __builtin_amdgcn_mfma_f32_16x16x32_bf16(wf[mt*2+1], B1.v, acc[mt], 0,0,0);
        }
        u16* orow = out + (size_t)p*64;
        #pragma unroll
        for (int mt = 0; mt < 4; ++mt){
            float v0 = acc[mt].x + bv[mt].x;
            float v1 = acc[mt].y + bv[mt].y;
            float v2 = acc[mt].z + bv[mt].z;
            float v3 = acc[mt].w + bv[mt].w;
            st1[mt*4+0] += v0; st2[mt*4+0] += v0*v0;
            st1[mt*4+1] += v1; st2[mt*4+1] += v1*v1;
            st1[mt*4+2] += v2; st2[mt*4+2] += v2*v2;
            st1[mt*4+3] += v3; st2[mt*4+3] += v3*v3;
            uint2 pk;
            pk.x = f2bf(v0) | (f2bf(v1) << 16);
            pk.y = f2bf(v2) | (f2bf(v3) << 16);
            *(uint2*)(orow + mt*16 + q*4) = pk;
        }
    }
    #pragma unroll
    for (int e = 0; e < 16; ++e){
        float r1 = row_sum16(st1[e]);
        float r2 = row_sum16(st2[e]);
        if (n == 15){
            const int ch = (e >> 2)*16 + q*4 + (e & 3);
            sStat[wv*128 + ch]      = r1;
            sStat[wv*128 + 64 + ch] = r2;
        }
    }
    __syncthreads();
    if (t < 128){
        float s = sStat[t] + sStat[128+t] + sStat[256+t] + sStat[384+t];
        pout[(size_t)bb*128 + t] = s;
    }
}

// ---------------------------------------------------------------------------
// Residual (bf16 rows): x2 = leaky(affV(v) + leaky(affY(yt))).
// ---------------------------------------------------------------------------
__global__ __launch_bounds__(256,2) void resid_kernel(const u16* __restrict__ v,
    const u16* __restrict__ yt, u16* __restrict__ x2,
    const float* __restrict__ affV, const float* __restrict__ affY)
{
    const int t = threadIdx.x;
    const int dc = t & 31, rg = t >> 5;
    const int c0 = dc*2, c1 = c0 + 1;
    const float va0 = affV[c0], vb0 = affV[64+c0];
    const float va1 = affV[c1], vb1 = affV[64+c1];
    const float ya0 = affY[c0], yb0 = affY[64+c0];
    const float ya1 = affY[c1], yb1 = affY[64+c1];
    const unsigned* vp = (const unsigned*)v;
    const unsigned* yp = (const unsigned*)yt;
    unsigned* xp = (unsigned*)x2;
    const size_t base = (size_t)blockIdx.x*512;
    #pragma unroll 4
    for (int r = rg; r < 512; r += 8){
        const size_t e = (base + r)*32 + dc;
        unsigned uv = vp[e], uy = yp[e];
        float r0 = lrelu(fmaf(va0, bflo(uv), vb0) + lrelu(fmaf(ya0, bflo(uy), yb0)));
        float r1 = lrelu(fmaf(va1, bfhi(uv), vb1) + lrelu(fmaf(ya1, bfhi(uy), yb1)));
        xp[e] = f2bf(r0) | (f2bf(r1) << 16);
    }
}

// ---------------------------------------------------------------------------
// Final: x3 = leaky(aff(v2) + x2); out1[b,c,s] = max over the 32 K-rows.
// ---------------------------------------------------------------------------
__global__ __launch_bounds__(256,2) void final_kernel(const u16* __restrict__ v2,
    const u16* __restrict__ x2, const float* __restrict__ aff,
    float* __restrict__ out1)
{
    const int t = threadIdx.x;
    const int dc = t & 31, sg = t >> 5;
    const int c0 = dc*2, c1 = c0 + 1;
    const float a0 = aff[c0], s0 = aff[64+c0];
    const float a1 = aff[c1], s1 = aff[64+c1];
    const int s = blockIdx.x*8 + sg;
    const unsigned* vp = (const unsigned*)v2;
    const unsigned* xp = (const unsigned*)x2;
    float m0 = -3.0e38f, m1 = -3.0e38f;
    #pragma unroll 8
    for (int kk = 0; kk < 32; ++kk){
        const size_t e = ((size_t)s*32 + kk)*32 + dc;
        unsigned uv = vp[e], ux = xp[e];
        m0 = fmaxf(m0, lrelu(fmaf(a0, bflo(uv), s0) + bflo(ux)));
        m1 = fmaxf(m1, lrelu(fmaf(a1, bfhi(uv), s1) + bfhi(ux)));
    }
    const int b = s >> 10, sl = s & 1023;
    out1[((size_t)b*NC + c0)*NS + sl] = m0;
    out1[((size_t)b*NC + c1)*NS + sl] = m1;
}

// ---------------------------------------------------------------------------
extern "C" void kernel_launch(void* const* d_in, const int* in_sizes, int n_in,
                              void* d_out, int out_size, void* d_ws, size_t ws_size,
                              hipStream_t stream)
{
    const float* xyz      = (const float*)d_in[0];
    const float* features = (const float*)d_in[1];
    const float* w_t    = (const float*)d_in[2];
    const float* w1_0   = (const float*)d_in[3];
    const float* w2_0   = (const float*)d_in[4];
    const float* w1_1   = (const float*)d_in[5];
    const float* w2_1   = (const float*)d_in[6];
    const float* b_t    = (const float*)d_in[7];
    const float* b1_0   = (const float*)d_in[8];
    const float* b2_0   = (const float*)d_in[9];
    const float* b1_1   = (const float*)d_in[10];
    const float* b2_1   = (const float*)d_in[11];
    const float* g_t    = (const float*)d_in[12];
    const float* g1_0   = (const float*)d_in[13];
    const float* g2_0   = (const float*)d_in[14];
    const float* g1_1   = (const float*)d_in[15];
    const float* g2_1   = (const float*)d_in[16];
    const float* beta_t  = (const float*)d_in[17];
    const float* beta1_0 = (const float*)d_in[18];
    const float* beta2_0 = (const float*)d_in[19];
    const float* beta1_1 = (const float*)d_in[20];
    const float* beta2_1 = (const float*)d_in[21];

    float* out = (float*)d_out;

    float* nxyz = (float*)d_ws;                          // 24576 f
    int*   kidx = (int*)(nxyz + 24576);                  // NP ints
    float* pT   = (float*)(kidx + NP);                   // 5 x 1024*128 partials
    float* p10  = pT  + 131072;
    float* p20  = p10 + 131072;
    float* p11  = p20 + 131072;
    float* p21  = p11 + 131072;
    float* affT  = p21 + 131072;                         // 5 x 128
    float* aff10 = affT + 128;
    float* aff20 = aff10 + 128;
    float* aff11 = aff20 + 128;
    float* aff21 = aff11 + 128;
    u16*  bwt  = (u16*)(aff21 + 128);                    // 5*4096 u16
    u16*  buf0 = bwt + 5*4096;                           // 3 x NP*64 bf16
    u16*  buf1 = buf0 + (size_t)NP*NC;
    u16*  buf2 = buf1 + (size_t)NP*NC;

    wtrans_kernel<<<5, 256, 0, stream>>>(w_t, w1_0, w2_0, w1_1, w2_1, bwt);
    fps_kernel<<<NB, 256, 0, stream>>>(xyz, out, nxyz);
    knn_kernel<<<NQ/4, 256, 0, stream>>>(xyz, nxyz, kidx);

    // conv_t (gather fused) -> buf1, stats pT
    gconv_mfma_kernel<<<1024, 256, 0, stream>>>(features, kidx, buf1,
                                                bwt + 0*4096, b_t, pT);
    finalize_kernel<<<1, 1024, 0, stream>>>(pT, g_t, beta_t, affT);
    // resblock 0
    conv_mfma_kernel<1><<<1024, 256, 0, stream>>>(buf1, buf0, bwt + 1*4096, b1_0,
                                                  affT, p10);
    finalize_kernel<<<1, 1024, 0, stream>>>(p10, g1_0, beta1_0, aff10);
    conv_mfma_kernel<1><<<1024, 256, 0, stream>>>(buf0, buf2, bwt + 2*4096, b2_0,
                                                  aff10, p20);
    finalize_kernel<<<1, 1024, 0, stream>>>(p20, g2_0, beta2_0, aff20);
    resid_kernel<<<512, 256, 0, stream>>>(buf2, buf1, buf0, aff20, affT);
    // resblock 1 (input already activated)
    conv_mfma_kernel<0><<<1024, 256, 0, stream>>>(buf0, buf1, bwt + 3*4096, b1_1,
                                                  nullptr, p11);
    finalize_kernel<<<1, 1024, 0, stream>>>(p11, g1_1, beta1_1, aff11);
    conv_mfma_kernel<1><<<1024, 256, 0, stream>>>(buf1, buf2, bwt + 4*4096, b2_1,
                                                  aff11, p21);
    finalize_kernel<<<1, 1024, 0, stream>>>(p21, g2_1, beta2_1, aff21);
    // epilogue: residual + max over K
    final_kernel<<<1024, 256, 0, stream>>>(buf2, buf0, aff21,
                                           out + (size_t)NB*3*NS);
}